// Round 11
// baseline (202.589 us; speedup 1.0000x reference)
//
#include <hip/hip_runtime.h>
#include <stdint.h>
#include <stddef.h>

// T=2048, B=4, E=1024, H=16, HD=64, N-heads = B*H = 64.
// qkv reshape: f in [0,3072) -> head hq = f/192, s3 = (f/64)%3, d = f%64, n = b*16+hq.
// Layouts: Qb,Kb,Vb = [n][t][d] bf16 ; VTb = [n][d][t] bf16 (separate transpose kernel).

typedef __attribute__((ext_vector_type(8))) short bf16x8;
typedef __attribute__((ext_vector_type(4))) float f32x4;
typedef __attribute__((ext_vector_type(4))) unsigned int u32x4;

#define MFMA16(a, b, c) __builtin_amdgcn_mfma_f32_16x16x32_bf16((a), (b), (c), 0, 0, 0)

__device__ __forceinline__ unsigned short f2bf(float f) {
  unsigned u = __builtin_bit_cast(unsigned, f);
  u += 0x7fffu + ((u >> 16) & 1u);   // RNE
  return (unsigned short)(u >> 16);
}

__device__ __forceinline__ float fast_exp2(float x) {
#if __has_builtin(__builtin_amdgcn_exp2f)
  return __builtin_amdgcn_exp2f(x);
#else
  return exp2f(x);
#endif
}

__device__ __forceinline__ unsigned cvtpk(float lo, float hi) {
  unsigned r;
  asm volatile("v_cvt_pk_bf16_f32 %0, %1, %2" : "=v"(r) : "v"(lo), "v"(hi));
  return r;
}

// a' = {a.lo32, b.lo32}, b' = {a.hi32, b.hi32}
__device__ __forceinline__ void lane_swap32(unsigned &a, unsigned &b) {
#if __has_builtin(__builtin_amdgcn_permlane32_swap)
  auto r = __builtin_amdgcn_permlane32_swap(a, b, false, false);
  a = r[0]; b = r[1];
#else
  const bool hi = (threadIdx.x & 32) != 0;
  unsigned sa = (unsigned)__shfl_xor((int)a, 32, 64);
  unsigned sb = (unsigned)__shfl_xor((int)b, 32, 64);
  unsigned na = hi ? sb : a;
  unsigned nb = hi ? b : sa;
  a = na; b = nb;
#endif
}

// a' = {a.g0, b.g0, a.g2, b.g2}, b' = {a.g1, b.g1, a.g3, b.g3} (16-lane groups)
__device__ __forceinline__ void lane_swap16(unsigned &a, unsigned &b) {
#if __has_builtin(__builtin_amdgcn_permlane16_swap)
  auto r = __builtin_amdgcn_permlane16_swap(a, b, false, false);
  a = r[0]; b = r[1];
#else
  const bool odd = (threadIdx.x & 16) != 0;
  unsigned sa = (unsigned)__shfl_xor((int)a, 16, 64);
  unsigned sb = (unsigned)__shfl_xor((int)b, 16, 64);
  unsigned na = odd ? sb : a;
  unsigned nb = odd ? b : sa;
  a = na; b = nb;
#endif
}

__device__ __forceinline__ void gload_lds16(const void* g, void* l) {
  __builtin_amdgcn_global_load_lds((const __attribute__((address_space(1))) void*)g,
                                   (__attribute__((address_space(3))) void*)l,
                                   16, 0, 0);
}

// ---------------- fused fp32 -> bf16 convert for X, W1, Wo ----------------
__global__ __launch_bounds__(256) void k_cvt3(const float* __restrict__ X,
                                              const float* __restrict__ W1,
                                              const float* __restrict__ Wo,
                                              unsigned short* __restrict__ Xb,
                                              unsigned short* __restrict__ W1b,
                                              unsigned short* __restrict__ Wob) {
  int i = blockIdx.x * 256 + threadIdx.x;   // float4 index over all three buffers
  const float* src;
  unsigned short* dst;
  int j;
  if (i < 2097152) { src = X; dst = Xb; j = i; }
  else if (i < 2097152 + 786432) { src = W1; dst = W1b; j = i - 2097152; }
  else { src = Wo; dst = Wob; j = i - (2097152 + 786432); }
  const float4 v = ((const float4*)src)[j];
  ushort4 o;
  o.x = f2bf(v.x); o.y = f2bf(v.y); o.z = f2bf(v.z); o.w = f2bf(v.w);
  ((ushort4*)dst)[j] = o;
}

// ---------------- GEMM1: X[8192][1024] x W1t[3072][1024] -> scatter Q/K/V (R5 128² baseline) ----------------
__global__ __launch_bounds__(256, 2) void k_gemm_qkv(
    const unsigned short* __restrict__ A,
    const unsigned short* __restrict__ Bt,
    unsigned short* __restrict__ Qb,        // [64][2048][64]
    unsigned short* __restrict__ Kb,        // [64][2048][64]
    unsigned short* __restrict__ Vb) {      // [64][2048][64]
  constexpr int K = 1024;
  __shared__ __align__(16) unsigned short As[128 * 32];
  __shared__ __align__(16) unsigned short Bs[128 * 32];
  const int tid = threadIdx.x;
  const int l = tid & 63, w = tid >> 6;
  const int lr = l & 15, lg = l >> 4;
  const int bm = blockIdx.x, bn = blockIdx.y;
  const int wr = (w >> 1) * 64, wc = (w & 1) * 64;

  f32x4 acc[4][4] = {};

  const int o0 = tid * 16, o1 = tid * 16 + 4096;
  const int r0 = o0 >> 6, c0 = o0 & 63;
  const int r1 = o1 >> 6, c1 = o1 & 63;
  const char* gA0 = (const char*)A + (size_t)(bm * 128 + r0) * (K * 2) + c0;
  const char* gA1 = (const char*)A + (size_t)(bm * 128 + r1) * (K * 2) + c1;
  const char* gB0 = (const char*)Bt + (size_t)(bn * 128 + r0) * (K * 2) + c0;
  const char* gB1 = (const char*)Bt + (size_t)(bn * 128 + r1) * (K * 2) + c1;
  char* lA0 = (char*)As + o0;
  char* lA1 = (char*)As + o1;
  char* lB0 = (char*)Bs + o0;
  char* lB1 = (char*)Bs + o1;

  for (int kt = 0; kt < K / 32; ++kt) {
    const int kb = kt * 64;
    gload_lds16(gA0 + kb, lA0);
    gload_lds16(gA1 + kb, lA1);
    gload_lds16(gB0 + kb, lB0);
    gload_lds16(gB1 + kb, lB1);
    __syncthreads();
    bf16x8 af[4], bfr[4];
#pragma unroll
    for (int mf = 0; mf < 4; ++mf)
      af[mf] = *(const bf16x8*)&As[(wr + mf * 16 + lr) * 32 + lg * 8];
#pragma unroll
    for (int nf = 0; nf < 4; ++nf)
      bfr[nf] = *(const bf16x8*)&Bs[(wc + nf * 16 + lr) * 32 + lg * 8];
#pragma unroll
    for (int mf = 0; mf < 4; ++mf)
#pragma unroll
      for (int nf = 0; nf < 4; ++nf)
        acc[mf][nf] = MFMA16(af[mf], bfr[nf], acc[mf][nf]);
    __syncthreads();
  }

  // D layout: col = lane&15, row = (lane>>4)*4 + i. Coalesced [n][t][d] for Q,K,V.
#pragma unroll
  for (int nf = 0; nf < 4; ++nf) {
    const int f = bn * 128 + wc + nf * 16 + lr;
    const int hq = f / 192;
    const int s3 = (f >> 6) % 3;
    const int d = f & 63;
    unsigned short* dst = (s3 == 0) ? Qb : (s3 == 1) ? Kb : Vb;
    // fold SCALE*log2(e) into Q so softmax is a bare exp2
    const float qscale = (s3 == 0) ? 0.18033688011112042f : 1.0f;
#pragma unroll
    for (int mf = 0; mf < 4; ++mf) {
#pragma unroll
      for (int i = 0; i < 4; ++i) {
        const int r = bm * 128 + wr + mf * 16 + lg * 4 + i;
        const int t = r >> 2, bb2 = r & 3;
        const int nIdx = bb2 * 16 + hq;
        dst[((size_t)nIdx * 2048 + t) * 64 + d] = f2bf(acc[mf][nf][i] * qscale);
      }
    }
  }
}

// ---------------- V transpose: [n][t][d] -> [n][d][t] ----------------
__global__ __launch_bounds__(256) void k_vtrans(const unsigned short* __restrict__ V,
                                                unsigned short* __restrict__ VT) {
  __shared__ unsigned short tile[64][66];
  const int tid = threadIdx.x;
  const int n = blockIdx.y, t0 = blockIdx.x * 64;
  const int r = tid >> 2, c0 = (tid & 3) * 16;
  const unsigned short* src = V + ((size_t)(n * 2048 + t0 + r) * 64 + c0);
  bf16x8 a = *(const bf16x8*)src;
  bf16x8 b = *(const bf16x8*)(src + 8);
#pragma unroll
  for (int j = 0; j < 8; ++j) tile[r][c0 + j] = (unsigned short)a[j];
#pragma unroll
  for (int j = 0; j < 8; ++j) tile[r][c0 + 8 + j] = (unsigned short)b[j];
  __syncthreads();
  const int d = tid >> 2, u0 = (tid & 3) * 16;
  bf16x8 oA, oB;
#pragma unroll
  for (int j = 0; j < 8; ++j) oA[j] = (short)tile[u0 + j][d];
#pragma unroll
  for (int j = 0; j < 8; ++j) oB[j] = (short)tile[u0 + 8 + j][d];
  unsigned short* dst = VT + ((size_t)(n * 64 + d) * 2048 + t0 + u0);
  *(bf16x8*)dst = oA;
  *(bf16x8*)(dst + 8) = oB;
}

// ---------------- flash attention: 1 wave/block, KVBLK=32, barrier-free own-wave pipeline ----------------
__global__ __launch_bounds__(64, 2) void k_attn(
    const unsigned short* __restrict__ Qb, const unsigned short* __restrict__ Kb,
    const unsigned short* __restrict__ VTb, unsigned short* __restrict__ Cx) {
  // Per-wave private double buffers (no cross-wave sharing -> no barriers).
  __shared__ __align__(16) unsigned short Ks[2][32 * 64];  // [s][d] rows 128B, swz (row&7)<<4
  __shared__ __align__(16) unsigned short Vt[2][64 * 32];  // [d][s] rows 64B, swz ((row>>1)&3)<<4

  const int l = threadIdx.x;          // 0..63 (one wave)
  const int lq = l & 15, lg = l >> 4;
  const int n = blockIdx.x, qt = blockIdx.y;   // x = head -> same-head blocks on one XCD

  const unsigned short* Qh = Qb + (size_t)n * (2048 * 64);
  const unsigned short* Kh = Kb + (size_t)n * (2048 * 64);
  const unsigned short* Vh = VTb + (size_t)n * (64 * 2048);

  // Q fragments (B-operand of swapped QK^T): q = qt*64 + qf*16 + lq
  bf16x8 aq[4][2];
#pragma unroll
  for (int qf = 0; qf < 4; ++qf)
#pragma unroll
    for (int kd = 0; kd < 2; ++kd)
      aq[qf][kd] = *(const bf16x8*)&Qh[(size_t)(qt * 64 + qf * 16 + lq) * 64 +
                                       kd * 32 + lg * 8];

  f32x4 o[4][4] = {};       // O^T acc: [df][qf]; lane: q = lq, d = df*16 + lg*4 + i
  float lsum[4] = {0.f, 0.f, 0.f, 0.f};

  char* KsB = (char*)&Ks[0][0];
  char* VtB = (char*)&Vt[0][0];

  // stage K(4KB) + V^T(4KB) for a 32-key tile: 8 gload_lds per lane, own-wave only
  auto STAGE = [&](int buf, int st) {
    const int s0 = st * 32;
#pragma unroll
    for (int it = 0; it < 4; ++it) {
      const int idx = it * 64 + l;              // 0..255 16B-slots
      const int krow = idx >> 3;                // 0..31
      const int kcol = (idx & 7) * 16;
      gload_lds16((const char*)Kh + ((size_t)(s0 + krow) << 7) + (kcol ^ ((krow & 7) << 4)),
                  KsB + buf * 4096 + idx * 16);
      const int vrow = idx >> 2;                // 0..63
      const int vcol = (idx & 3) * 16;
      gload_lds16((const char*)Vh + ((size_t)vrow << 12) + (s0 << 1) +
                      (vcol ^ (((vrow >> 1) & 3) << 4)),
                  VtB + buf * 4096 + idx * 16);
    }
  };

  STAGE(0, 0);
  asm volatile("s_waitcnt vmcnt(0)" ::: "memory");

#pragma unroll 2
  for (int st = 0; st < 64; ++st) {
    const int cur = st & 1;
    if (st + 1 < 64) STAGE(cur ^ 1, st + 1);   // prefetch next tile (own-wave, other buffer)

    const char* Kc = KsB + cur * 4096;
    const char* Vc = VtB + cur * 4096;

    __builtin_amdgcn_s_setprio(1);
    // K fragments: rows sfl*16 + lq
    bf16x8 kf[2][2];
#pragma unroll
    for (int sfl = 0; sfl < 2; ++sfl) {
      const int rowk = sfl * 16 + lq;
      const int sw = (rowk & 7) << 4;
      kf[sfl][0] = *(const bf16x8*)(Kc + ((rowk * 128 + lg * 16) ^ sw));
      kf[sfl][1] = *(const bf16x8*)(Kc + ((rowk * 128 + 64 + lg * 16) ^ sw));
    }

    // QK^T + softmax + in-register P->B-frag exchange, per qf
    bf16x8 pq[4];
#pragma unroll
    for (int qf = 0; qf < 4; ++qf) {
      f32x4 s0 = {0.f, 0.f, 0.f, 0.f};
      f32x4 s1 = {0.f, 0.f, 0.f, 0.f};
      s0 = MFMA16(kf[0][0], aq[qf][0], s0);
      s0 = MFMA16(kf[0][1], aq[qf][1], s0);
      s1 = MFMA16(kf[1][0], aq[qf][0], s1);
      s1 = MFMA16(kf[1][1], aq[qf][1], s1);
      float accs = 0.f;
#pragma unroll
      for (int i = 0; i < 4; ++i) {
        s0[i] = fast_exp2(s0[i]);
        s1[i] = fast_exp2(s1[i]);
        accs += s0[i] + s1[i];
      }
      lsum[qf] += accs;
      unsigned w0 = cvtpk(s0[0], s0[1]);
      unsigned w1 = cvtpk(s0[2], s0[3]);
      unsigned w2 = cvtpk(s1[0], s1[1]);
      unsigned w3 = cvtpk(s1[2], s1[3]);
      lane_swap32(w0, w2);
      lane_swap32(w1, w3);
      lane_swap16(w0, w2);
      lane_swap16(w1, w3);
      u32x4 t4 = {w0, w1, w2, w3};
      pq[qf] = __builtin_bit_cast(bf16x8, t4);
    }

    // PV: O^T += V^T . P^T
#pragma unroll
    for (int df = 0; df < 4; ++df) {
      const int rowd = df * 16 + lq;
      const int sw = ((rowd >> 1) & 3) << 4;
      bf16x8 vf = *(const bf16x8*)(Vc + ((rowd * 64 + lg * 16) ^ sw));
#pragma unroll
      for (int qf = 0; qf < 4; ++qf)
        o[df][qf] = MFMA16(vf, pq[qf], o[df][qf]);
    }
    __builtin_amdgcn_s_setprio(0);

    // own-wave drain: next tile's 8 loads complete before next iteration reads them
    asm volatile("s_waitcnt vmcnt(0)" ::: "memory");
  }

  // epilogue: reduce lsum over lane-groups, normalize, store
  const int bb = n >> 4, h = n & 15;
#pragma unroll
  for (int qf = 0; qf < 4; ++qf) {
    float li = lsum[qf];
    li += __shfl_xor(li, 16, 64);
    li += __shfl_xor(li, 32, 64);
    const float inv = 1.0f / li;
    const int q = qt * 64 + qf * 16 + lq;
#pragma unroll
    for (int df = 0; df < 4; ++df) {
      ushort4 pk;
      pk.x = f2bf(o[df][qf][0] * inv);
      pk.y = f2bf(o[df][qf][1] * inv);
      pk.z = f2bf(o[df][qf][2] * inv);
      pk.w = f2bf(o[df][qf][3] * inv);
      *(ushort4*)&Cx[(size_t)(q * 4 + bb) * 1024 + h * 64 + df * 16 + lg * 4] = pk;
    }
  }
}

// ---------------- GEMM4: ctx[8192][1024] x Wot[1024][1024] -> out fp32 ----------------
__global__ __launch_bounds__(256, 2) void k_gemm_out(
    const unsigned short* __restrict__ A,
    const unsigned short* __restrict__ Bt,
    float* __restrict__ C) {
  constexpr int K = 1024;
  __shared__ __align__(16) unsigned short As[128 * 32];
  __shared__ __align__(16) unsigned short Bs[128 * 32];
  const int tid = threadIdx.x;
  const int l = tid & 63, w = tid >> 6;
  const int lr = l & 15, lg = l >> 4;
  const int bm = blockIdx.x, bn = blockIdx.y;
  const int wr = (w >> 1) * 64, wc = (w & 1) * 64;

  f32x4 acc[4][4] = {};

  const int o0 = tid * 16, o1 = tid * 16 + 4096;
  const int r0 = o0 >> 6, c0 = o0 & 63;
  const int r1 = o1 >> 6, c1 = o1 & 63;
  const char* gA0 = (const char*)A + (size_t)(bm * 128 + r0) * (K * 2) + c0;
  const char* gA1 = (const char*)A + (size_t)(bm * 128 + r1) * (K * 2) + c1;
  const char* gB0 = (const char*)Bt + (size_t)(bn * 128 + r0) * (K * 2) + c0;
  const char* gB1 = (const char*)Bt + (size_t)(bn * 128 + r1) * (K * 2) + c1;
  char* lA0 = (char*)As + o0;
  char* lA1 = (char*)As + o1;
  char* lB0 = (char*)Bs + o0;
  char* lB1 = (char*)Bs + o1;

  for (int kt = 0; kt < K / 32; ++kt) {
    const int kb = kt * 64;
    gload_lds16(gA0 + kb, lA0);
    gload_lds16(gA1 + kb, lA1);
    gload_lds16(gB0 + kb, lB0);
    gload_lds16(gB1 + kb, lB1);
    __syncthreads();
    bf16x8 af[4], bfr[4];
#pragma unroll
    for (int mf = 0; mf < 4; ++mf)
      af[mf] = *(const bf16x8*)&As[(wr + mf * 16 + lr) * 32 + lg * 8];
#pragma unroll
    for (int nf = 0; nf < 4; ++nf)
      bfr[nf] = *(const bf16x8*)&Bs[(wc + nf * 16 + lr) * 32 + lg * 8];
#pragma unroll
    for (int mf = 0; mf < 4; ++mf)
#pragma unroll
      for (int nf = 0; nf < 4; ++nf)
        acc[mf][nf] = MFMA16(af[mf], bfr[nf], acc[mf][nf]);
    __syncthreads();
  }

#pragma unroll
  for (int mf = 0; mf < 4; ++mf)
#pragma unroll
    for (int i = 0; i < 4; ++i) {
      const int r = bm * 128 + wr + mf * 16 + lg * 4 + i;
#pragma unroll
      for (int nf = 0; nf < 4; ++nf)
        C[(size_t)r * 1024 + bn * 128 + wc + nf * 16 + lr] = acc[mf][nf][i];
    }
}

// ---------------- host launch ----------------
extern "C" void kernel_launch(void* const* d_in, const int* in_sizes, int n_in,
                              void* d_out, int out_size, void* d_ws, size_t ws_size,
                              hipStream_t stream) {
  const float* X = (const float*)d_in[0];    // (2048,4,1024)
  const float* W1 = (const float*)d_in[1];   // (3072,1024)
  const float* Wo = (const float*)d_in[2];   // (1024,1024)
  float* out = (float*)d_out;                // (2048,4,1024) fp32

  char* ws = (char*)d_ws;
  unsigned short* Xb  = (unsigned short*)(ws);              // 16 MB
  unsigned short* W1b = (unsigned short*)(ws + 16777216);   //  6 MB
  unsigned short* Wob = (unsigned short*)(ws + 23068672);   //  2 MB
  unsigned short* Qb  = (unsigned short*)(ws + 25165824);   // 16 MB
  unsigned short* Kb  = (unsigned short*)(ws + 41943040);   // 16 MB
  unsigned short* VTb = (unsigned short*)(ws + 58720256);   // 16 MB
  // Vb aliases the Cx slot: Vb is dead after k_vtrans, Cx written only by k_attn (later).
  unsigned short* Vb  = (unsigned short*)(ws + 75497472);   // 16 MB
  unsigned short* Cx  = (unsigned short*)(ws + 75497472);   // same 16 MB

  k_cvt3<<<12288, 256, 0, stream>>>(X, W1, Wo, Xb, W1b, Wob);
  k_gemm_qkv<<<dim3(64, 24), 256, 0, stream>>>(Xb, W1b, Qb, Kb, Vb);
  k_vtrans<<<dim3(32, 64), 256, 0, stream>>>(Vb, VTb);
  k_attn<<<dim3(64, 32), 64, 0, stream>>>(Qb, Kb, VTb, Cx);
  k_gemm_out<<<dim3(64, 8), 256, 0, stream>>>(Cx, Wob, out);
}

// Round 13
// 186.713 us; speedup vs baseline: 1.0850x; 1.0850x over previous
//
#include <hip/hip_runtime.h>
#include <stdint.h>
#include <stddef.h>

// T=2048, B=4, E=1024, H=16, HD=64, N-heads = B*H = 64.
// qkv reshape: f in [0,3072) -> head hq = f/192, s3 = (f/64)%3, d = f%64, n = b*16+hq.
// Layouts: Qb,Kb = [n][t][d] bf16 ; VTb = [n][d][t] bf16 (transposed in GEMM epilogue via LDS).

typedef __attribute__((ext_vector_type(8))) short bf16x8;
typedef __attribute__((ext_vector_type(4))) float f32x4;
typedef __attribute__((ext_vector_type(4))) unsigned int u32x4;

#define MFMA16(a, b, c) __builtin_amdgcn_mfma_f32_16x16x32_bf16((a), (b), (c), 0, 0, 0)

__device__ __forceinline__ unsigned short f2bf(float f) {
  unsigned u = __builtin_bit_cast(unsigned, f);
  u += 0x7fffu + ((u >> 16) & 1u);   // RNE
  return (unsigned short)(u >> 16);
}

__device__ __forceinline__ float fast_exp2(float x) {
#if __has_builtin(__builtin_amdgcn_exp2f)
  return __builtin_amdgcn_exp2f(x);
#else
  return exp2f(x);
#endif
}

__device__ __forceinline__ unsigned cvtpk(float lo, float hi) {
  unsigned r;
  asm volatile("v_cvt_pk_bf16_f32 %0, %1, %2" : "=v"(r) : "v"(lo), "v"(hi));
  return r;
}

// a' = {a.lo32, b.lo32}, b' = {a.hi32, b.hi32}
__device__ __forceinline__ void lane_swap32(unsigned &a, unsigned &b) {
#if __has_builtin(__builtin_amdgcn_permlane32_swap)
  auto r = __builtin_amdgcn_permlane32_swap(a, b, false, false);
  a = r[0]; b = r[1];
#else
  const bool hi = (threadIdx.x & 32) != 0;
  unsigned sa = (unsigned)__shfl_xor((int)a, 32, 64);
  unsigned sb = (unsigned)__shfl_xor((int)b, 32, 64);
  unsigned na = hi ? sb : a;
  unsigned nb = hi ? b : sa;
  a = na; b = nb;
#endif
}

// a' = {a.g0, b.g0, a.g2, b.g2}, b' = {a.g1, b.g1, a.g3, b.g3} (16-lane groups)
__device__ __forceinline__ void lane_swap16(unsigned &a, unsigned &b) {
#if __has_builtin(__builtin_amdgcn_permlane16_swap)
  auto r = __builtin_amdgcn_permlane16_swap(a, b, false, false);
  a = r[0]; b = r[1];
#else
  const bool odd = (threadIdx.x & 16) != 0;
  unsigned sa = (unsigned)__shfl_xor((int)a, 16, 64);
  unsigned sb = (unsigned)__shfl_xor((int)b, 16, 64);
  unsigned na = odd ? sb : a;
  unsigned nb = odd ? b : sa;
  a = na; b = nb;
#endif
}

__device__ __forceinline__ void gload_lds16(const void* g, void* l) {
  __builtin_amdgcn_global_load_lds((const __attribute__((address_space(1))) void*)g,
                                   (__attribute__((address_space(3))) void*)l,
                                   16, 0, 0);
}

// ---------------- fused fp32 -> bf16 convert for X, W1, Wo ----------------
__global__ __launch_bounds__(256) void k_cvt3(const float* __restrict__ X,
                                              const float* __restrict__ W1,
                                              const float* __restrict__ Wo,
                                              unsigned short* __restrict__ Xb,
                                              unsigned short* __restrict__ W1b,
                                              unsigned short* __restrict__ Wob) {
  int i = blockIdx.x * 256 + threadIdx.x;   // float4 index over all three buffers
  const float* src;
  unsigned short* dst;
  int j;
  if (i < 2097152) { src = X; dst = Xb; j = i; }
  else if (i < 2097152 + 786432) { src = W1; dst = W1b; j = i - 2097152; }
  else { src = Wo; dst = Wob; j = i - (2097152 + 786432); }
  const float4 v = ((const float4*)src)[j];
  ushort4 o;
  o.x = f2bf(v.x); o.y = f2bf(v.y); o.z = f2bf(v.z); o.w = f2bf(v.w);
  ((ushort4*)dst)[j] = o;
}

// ---------------- GEMM1: X[8192][1024] x W1t[3072][1024] -> Q/K direct + V transposed ----------------
__global__ __launch_bounds__(256, 2) void k_gemm_qkv(
    const unsigned short* __restrict__ A,
    const unsigned short* __restrict__ Bt,
    unsigned short* __restrict__ Qb,        // [64][2048][64]
    unsigned short* __restrict__ Kb,        // [64][2048][64]
    unsigned short* __restrict__ VTb) {     // [64][64][2048]
  constexpr int K = 1024;
  // Sm: main loop uses [0..4095] as A-tile, [4096..8191] as B-tile (8KB each).
  // Epilogue reuses all 17408B as a 128x68-pitch bf16 transpose buffer for the V group.
  __shared__ __align__(16) unsigned short Sm[8704];
  unsigned short* As = Sm;
  unsigned short* Bs = Sm + 4096;

  const int tid = threadIdx.x;
  const int l = tid & 63, w = tid >> 6;
  const int lr = l & 15, lg = l >> 4;
  const int bm = blockIdx.x, bn = blockIdx.y;
  const int wr = (w >> 1) * 64, wc = (w & 1) * 64;

  f32x4 acc[4][4] = {};

  const int o0 = tid * 16, o1 = tid * 16 + 4096;
  const int r0 = o0 >> 6, c0 = o0 & 63;
  const int r1 = o1 >> 6, c1 = o1 & 63;
  const char* gA0 = (const char*)A + (size_t)(bm * 128 + r0) * (K * 2) + c0;
  const char* gA1 = (const char*)A + (size_t)(bm * 128 + r1) * (K * 2) + c1;
  const char* gB0 = (const char*)Bt + (size_t)(bn * 128 + r0) * (K * 2) + c0;
  const char* gB1 = (const char*)Bt + (size_t)(bn * 128 + r1) * (K * 2) + c1;
  char* lA0 = (char*)As + o0;
  char* lA1 = (char*)As + o1;
  char* lB0 = (char*)Bs + o0;
  char* lB1 = (char*)Bs + o1;

  for (int kt = 0; kt < K / 32; ++kt) {
    const int kb = kt * 64;
    gload_lds16(gA0 + kb, lA0);
    gload_lds16(gA1 + kb, lA1);
    gload_lds16(gB0 + kb, lB0);
    gload_lds16(gB1 + kb, lB1);
    __syncthreads();
    bf16x8 af[4], bfr[4];
#pragma unroll
    for (int mf = 0; mf < 4; ++mf)
      af[mf] = *(const bf16x8*)&As[(wr + mf * 16 + lr) * 32 + lg * 8];
#pragma unroll
    for (int nf = 0; nf < 4; ++nf)
      bfr[nf] = *(const bf16x8*)&Bs[(wc + nf * 16 + lr) * 32 + lg * 8];
#pragma unroll
    for (int mf = 0; mf < 4; ++mf)
#pragma unroll
      for (int nf = 0; nf < 4; ++nf)
        acc[mf][nf] = MFMA16(af[mf], bfr[nf], acc[mf][nf]);
    __syncthreads();
  }

  // Epilogue. Per wave, its 64-col group (f0 = bn*128 + wc) is entirely Q, K, or V:
  // s3g = (f0>>6)%3, hqg = f0/192; for all three cases d = nf*16+lr exactly.
  const int f0 = bn * 128 + wc;
  const int s3g = (f0 >> 6) % 3;
  const int hqg = f0 / 192;

  if (s3g != 2) {
    unsigned short* dst = (s3g == 0) ? Qb : Kb;
    const float qscale = (s3g == 0) ? 0.18033688011112042f : 1.0f;  // SCALE*log2(e) into Q
#pragma unroll
    for (int nf = 0; nf < 4; ++nf) {
      const int d = nf * 16 + lr;
#pragma unroll
      for (int mf = 0; mf < 4; ++mf) {
#pragma unroll
        for (int i = 0; i < 4; ++i) {
          const int r = bm * 128 + wr + mf * 16 + lg * 4 + i;
          const int t = r >> 2, bb2 = r & 3;
          dst[((size_t)(bb2 * 16 + hqg) * 2048 + t) * 64 + d] = f2bf(acc[mf][nf][i] * qscale);
        }
      }
    }
  } else {
    // V group: bounce through LDS transpose buffer (pitch 68 shorts), rows rl in [0,128)
#pragma unroll
    for (int nf = 0; nf < 4; ++nf) {
      const int d = nf * 16 + lr;
#pragma unroll
      for (int mf = 0; mf < 4; ++mf) {
#pragma unroll
        for (int i = 0; i < 4; ++i) {
          const int rl = wr + mf * 16 + lg * 4 + i;
          Sm[rl * 68 + d] = f2bf(acc[mf][nf][i]);
        }
      }
    }
  }
  __syncthreads();
  if (s3g == 2) {
    // two V-waves (128 threads): u -> (d, t-half); store VT[n=bb*16+hqg][d][t] in 8B chunks
    const int u = (w >> 1) * 64 + l;   // 0..127
    const int d = u >> 1, th = u & 1;
#pragma unroll
    for (int bb = 0; bb < 4; ++bb) {
      const size_t base = ((size_t)(bb * 16 + hqg) * 64 + d) * 2048 + bm * 32 + th * 16;
#pragma unroll
      for (int tq = 0; tq < 4; ++tq) {
        ushort4 pk;
        pk.x = Sm[((th * 16 + tq * 4 + 0) * 4 + bb) * 68 + d];
        pk.y = Sm[((th * 16 + tq * 4 + 1) * 4 + bb) * 68 + d];
        pk.z = Sm[((th * 16 + tq * 4 + 2) * 4 + bb) * 68 + d];
        pk.w = Sm[((th * 16 + tq * 4 + 3) * 4 + bb) * 68 + d];
        *(ushort4*)&VTb[base + tq * 4] = pk;
      }
    }
  }
}

// ---------------- flash attention: q=256/block, 2-phase pipelined (R5 verified, 82us) ----------------
__global__ __launch_bounds__(256, 2) void k_attn(
    const unsigned short* __restrict__ Qb, const unsigned short* __restrict__ Kb,
    const unsigned short* __restrict__ VTb, unsigned short* __restrict__ Cx) {
  __shared__ __align__(16) unsigned short Ks[2][64 * 64];  // [s][d], xor-swizzled
  __shared__ __align__(16) unsigned short Vt[2][64 * 64];  // [d][s], xor-swizzled

  const int tid = threadIdx.x;
  const int l = tid & 63, w = tid >> 6;
  const int lq = l & 15, lg = l >> 4;
  const int n = blockIdx.x, qt = blockIdx.y;   // x = head -> same-head blocks on one XCD

  const unsigned short* Qh = Qb + (size_t)n * (2048 * 64);
  const unsigned short* Kh = Kb + (size_t)n * (2048 * 64);
  const unsigned short* Vh = VTb + (size_t)n * (64 * 2048);

  // Q fragments (B-operand of swapped QK^T): q = qt*256 + w*64 + qf*16 + lq
  bf16x8 aq[4][2];
#pragma unroll
  for (int qf = 0; qf < 4; ++qf)
#pragma unroll
    for (int kd = 0; kd < 2; ++kd)
      aq[qf][kd] = *(const bf16x8*)&Qh[(size_t)(qt * 256 + w * 64 + qf * 16 + lq) * 64 +
                                       kd * 32 + lg * 8];

  f32x4 o[4][4] = {};       // O^T acc: [df][qf]; lane: q = lq, d = df*16 + lg*4 + i
  float lsum[4] = {0.f, 0.f, 0.f, 0.f};

  char* Ksl = (char*)&Ks[0][0];
  char* Vtl = (char*)&Vt[0][0];

  auto STAGE = [&](int buf, int st) {
    const int s0 = st * 64;
#pragma unroll
    for (int it = 0; it < 2; ++it) {
      const int off = (it * 256 + tid) * 16;
      const int row = off >> 7;
      const int colb = (off & 127) ^ ((row & 7) << 4);
      gload_lds16((const char*)Kh + ((size_t)(s0 + row) << 7) + colb, Ksl + buf * 8192 + off);
      gload_lds16((const char*)Vh + ((size_t)row << 12) + (s0 << 1) + colb, Vtl + buf * 8192 + off);
    }
  };

  STAGE(0, 0);
  asm volatile("s_waitcnt vmcnt(0)" ::: "memory");
  __builtin_amdgcn_s_barrier();

#pragma unroll 2
  for (int st = 0; st < 32; ++st) {
    const int cur = st & 1;
    if (st + 1 < 32) STAGE(cur ^ 1, st + 1);   // prefetch next tile

    const char* Kc = Ksl + cur * 8192;
    const char* Vc = Vtl + cur * 8192;

    __builtin_amdgcn_s_setprio(1);
#pragma unroll
    for (int kb = 0; kb < 2; ++kb) {
      // K fragments for s-block [kb*32, kb*32+32): rows (2kb+sfl)*16 + lq
      bf16x8 kf[2][2];
#pragma unroll
      for (int sfl = 0; sfl < 2; ++sfl) {
        const int rowk = (2 * kb + sfl) * 16 + lq;
        const int sw = (rowk & 7) << 4;
        kf[sfl][0] = *(const bf16x8*)(Kc + ((rowk * 128 + lg * 16) ^ sw));
        kf[sfl][1] = *(const bf16x8*)(Kc + ((rowk * 128 + 64 + lg * 16) ^ sw));
      }

      // QK^T + softmax + in-register P->B-frag exchange, per qf
      bf16x8 pq[4];
#pragma unroll
      for (int qf = 0; qf < 4; ++qf) {
        f32x4 s0 = {0.f, 0.f, 0.f, 0.f};
        f32x4 s1 = {0.f, 0.f, 0.f, 0.f};
        s0 = MFMA16(kf[0][0], aq[qf][0], s0);
        s0 = MFMA16(kf[0][1], aq[qf][1], s0);
        s1 = MFMA16(kf[1][0], aq[qf][0], s1);
        s1 = MFMA16(kf[1][1], aq[qf][1], s1);
        float accs = 0.f;
#pragma unroll
        for (int i = 0; i < 4; ++i) {
          s0[i] = fast_exp2(s0[i]);
          s1[i] = fast_exp2(s1[i]);
          accs += s0[i] + s1[i];
        }
        lsum[qf] += accs;
        unsigned w0 = cvtpk(s0[0], s0[1]);
        unsigned w1 = cvtpk(s0[2], s0[3]);
        unsigned w2 = cvtpk(s1[0], s1[1]);
        unsigned w3 = cvtpk(s1[2], s1[3]);
        lane_swap32(w0, w2);
        lane_swap32(w1, w3);
        lane_swap16(w0, w2);
        lane_swap16(w1, w3);
        u32x4 t4 = {w0, w1, w2, w3};
        pq[qf] = __builtin_bit_cast(bf16x8, t4);
      }

      // PV for this s-block: O^T += V^T(:, kb) . P^T
#pragma unroll
      for (int df = 0; df < 4; ++df) {
        const int rowd = df * 16 + lq;
        const int sw = (rowd & 7) << 4;
        bf16x8 vf = *(const bf16x8*)(Vc + ((rowd * 128 + kb * 64 + lg * 16) ^ sw));
#pragma unroll
        for (int qf = 0; qf < 4; ++qf)
          o[df][qf] = MFMA16(vf, pq[qf], o[df][qf]);
      }
    }
    __builtin_amdgcn_s_setprio(0);

    asm volatile("s_waitcnt vmcnt(0)" ::: "memory");
    __builtin_amdgcn_s_barrier();
  }

  // epilogue: reduce lsum over lane-groups, normalize, store
  const int bb = n >> 4, h = n & 15;
#pragma unroll
  for (int qf = 0; qf < 4; ++qf) {
    float li = lsum[qf];
    li += __shfl_xor(li, 16, 64);
    li += __shfl_xor(li, 32, 64);
    const float inv = 1.0f / li;
    const int q = qt * 256 + w * 64 + qf * 16 + lq;
#pragma unroll
    for (int df = 0; df < 4; ++df) {
      ushort4 pk;
      pk.x = f2bf(o[df][qf][0] * inv);
      pk.y = f2bf(o[df][qf][1] * inv);
      pk.z = f2bf(o[df][qf][2] * inv);
      pk.w = f2bf(o[df][qf][3] * inv);
      *(ushort4*)&Cx[(size_t)(q * 4 + bb) * 1024 + h * 64 + df * 16 + lg * 4] = pk;
    }
  }
}

// ---------------- GEMM4: ctx[8192][1024] x Wot[1024][1024] -> out fp32 ----------------
__global__ __launch_bounds__(256, 2) void k_gemm_out(
    const unsigned short* __restrict__ A,
    const unsigned short* __restrict__ Bt,
    float* __restrict__ C) {
  constexpr int K = 1024;
  __shared__ __align__(16) unsigned short As[128 * 32];
  __shared__ __align__(16) unsigned short Bs[128 * 32];
  const int tid = threadIdx.x;
  const int l = tid & 63, w = tid >> 6;
  const int lr = l & 15, lg = l >> 4;
  const int bm = blockIdx.x, bn = blockIdx.y;
  const int wr = (w >> 1) * 64, wc = (w & 1) * 64;

  f32x4 acc[4][4] = {};

  const int o0 = tid * 16, o1 = tid * 16 + 4096;
  const int r0 = o0 >> 6, c0 = o0 & 63;
  const int r1 = o1 >> 6, c1 = o1 & 63;
  const char* gA0 = (const char*)A + (size_t)(bm * 128 + r0) * (K * 2) + c0;
  const char* gA1 = (const char*)A + (size_t)(bm * 128 + r1) * (K * 2) + c1;
  const char* gB0 = (const char*)Bt + (size_t)(bn * 128 + r0) * (K * 2) + c0;
  const char* gB1 = (const char*)Bt + (size_t)(bn * 128 + r1) * (K * 2) + c1;
  char* lA0 = (char*)As + o0;
  char* lA1 = (char*)As + o1;
  char* lB0 = (char*)Bs + o0;
  char* lB1 = (char*)Bs + o1;

  for (int kt = 0; kt < K / 32; ++kt) {
    const int kb = kt * 64;
    gload_lds16(gA0 + kb, lA0);
    gload_lds16(gA1 + kb, lA1);
    gload_lds16(gB0 + kb, lB0);
    gload_lds16(gB1 + kb, lB1);
    __syncthreads();
    bf16x8 af[4], bfr[4];
#pragma unroll
    for (int mf = 0; mf < 4; ++mf)
      af[mf] = *(const bf16x8*)&As[(wr + mf * 16 + lr) * 32 + lg * 8];
#pragma unroll
    for (int nf = 0; nf < 4; ++nf)
      bfr[nf] = *(const bf16x8*)&Bs[(wc + nf * 16 + lr) * 32 + lg * 8];
#pragma unroll
    for (int mf = 0; mf < 4; ++mf)
#pragma unroll
      for (int nf = 0; nf < 4; ++nf)
        acc[mf][nf] = MFMA16(af[mf], bfr[nf], acc[mf][nf]);
    __syncthreads();
  }

#pragma unroll
  for (int mf = 0; mf < 4; ++mf)
#pragma unroll
    for (int i = 0; i < 4; ++i) {
      const int r = bm * 128 + wr + mf * 16 + lg * 4 + i;
#pragma unroll
      for (int nf = 0; nf < 4; ++nf)
        C[(size_t)r * 1024 + bn * 128 + wc + nf * 16 + lr] = acc[mf][nf][i];
    }
}

// ---------------- host launch ----------------
extern "C" void kernel_launch(void* const* d_in, const int* in_sizes, int n_in,
                              void* d_out, int out_size, void* d_ws, size_t ws_size,
                              hipStream_t stream) {
  const float* X = (const float*)d_in[0];    // (2048,4,1024)
  const float* W1 = (const float*)d_in[1];   // (3072,1024)
  const float* Wo = (const float*)d_in[2];   // (1024,1024)
  float* out = (float*)d_out;                // (2048,4,1024) fp32

  char* ws = (char*)d_ws;
  unsigned short* Xb  = (unsigned short*)(ws);              // 16 MB
  unsigned short* W1b = (unsigned short*)(ws + 16777216);   //  6 MB
  unsigned short* Wob = (unsigned short*)(ws + 23068672);   //  2 MB
  unsigned short* Qb  = (unsigned short*)(ws + 25165824);   // 16 MB
  unsigned short* Kb  = (unsigned short*)(ws + 41943040);   // 16 MB
  unsigned short* VTb = (unsigned short*)(ws + 58720256);   // 16 MB
  unsigned short* Cx  = (unsigned short*)(ws + 75497472);   // 16 MB

  k_cvt3<<<12288, 256, 0, stream>>>(X, W1, Wo, Xb, W1b, Wob);
  k_gemm_qkv<<<dim3(64, 24), 256, 0, stream>>>(Xb, W1b, Qb, Kb, VTb);
  k_attn<<<dim3(64, 8), 256, 0, stream>>>(Qb, Kb, VTb, Cx);
  k_gemm_out<<<dim3(64, 8), 256, 0, stream>>>(Cx, Wob, out);
}

// Round 15
// 178.589 us; speedup vs baseline: 1.1344x; 1.0455x over previous
//
#include <hip/hip_runtime.h>
#include <stdint.h>
#include <stddef.h>

// T=2048, B=4, E=1024, H=16, HD=64, N-heads = B*H = 64.
// qkv reshape: f in [0,3072) -> head hq = f/192, s3 = (f/64)%3, d = f%64, n = b*16+hq.
// Layouts: Qb,Kb = [n][t][d] bf16 ; VTb = [n][d][t] bf16 (transposed in GEMM epilogue via LDS).

typedef __attribute__((ext_vector_type(8))) short bf16x8;
typedef __attribute__((ext_vector_type(4))) float f32x4;
typedef __attribute__((ext_vector_type(4))) unsigned int u32x4;

#define MFMA16(a, b, c) __builtin_amdgcn_mfma_f32_16x16x32_bf16((a), (b), (c), 0, 0, 0)

__device__ __forceinline__ unsigned short f2bf(float f) {
  unsigned u = __builtin_bit_cast(unsigned, f);
  u += 0x7fffu + ((u >> 16) & 1u);   // RNE
  return (unsigned short)(u >> 16);
}

__device__ __forceinline__ float fast_exp2(float x) {
#if __has_builtin(__builtin_amdgcn_exp2f)
  return __builtin_amdgcn_exp2f(x);
#else
  return exp2f(x);
#endif
}

__device__ __forceinline__ unsigned cvtpk(float lo, float hi) {
  unsigned r;
  asm volatile("v_cvt_pk_bf16_f32 %0, %1, %2" : "=v"(r) : "v"(lo), "v"(hi));
  return r;
}

// a' = {a.lo32, b.lo32}, b' = {a.hi32, b.hi32}
__device__ __forceinline__ void lane_swap32(unsigned &a, unsigned &b) {
#if __has_builtin(__builtin_amdgcn_permlane32_swap)
  auto r = __builtin_amdgcn_permlane32_swap(a, b, false, false);
  a = r[0]; b = r[1];
#else
  const bool hi = (threadIdx.x & 32) != 0;
  unsigned sa = (unsigned)__shfl_xor((int)a, 32, 64);
  unsigned sb = (unsigned)__shfl_xor((int)b, 32, 64);
  unsigned na = hi ? sb : a;
  unsigned nb = hi ? b : sa;
  a = na; b = nb;
#endif
}

// a' = {a.g0, b.g0, a.g2, b.g2}, b' = {a.g1, b.g1, a.g3, b.g3} (16-lane groups)
__device__ __forceinline__ void lane_swap16(unsigned &a, unsigned &b) {
#if __has_builtin(__builtin_amdgcn_permlane16_swap)
  auto r = __builtin_amdgcn_permlane16_swap(a, b, false, false);
  a = r[0]; b = r[1];
#else
  const bool odd = (threadIdx.x & 16) != 0;
  unsigned sa = (unsigned)__shfl_xor((int)a, 16, 64);
  unsigned sb = (unsigned)__shfl_xor((int)b, 16, 64);
  unsigned na = odd ? sb : a;
  unsigned nb = odd ? b : sa;
  a = na; b = nb;
#endif
}

__device__ __forceinline__ void gload_lds16(const void* g, void* l) {
  __builtin_amdgcn_global_load_lds((const __attribute__((address_space(1))) void*)g,
                                   (__attribute__((address_space(3))) void*)l,
                                   16, 0, 0);
}

// ---------------- fused fp32 -> bf16 convert for X, W1, Wo ----------------
__global__ __launch_bounds__(256) void k_cvt3(const float* __restrict__ X,
                                              const float* __restrict__ W1,
                                              const float* __restrict__ Wo,
                                              unsigned short* __restrict__ Xb,
                                              unsigned short* __restrict__ W1b,
                                              unsigned short* __restrict__ Wob) {
  int i = blockIdx.x * 256 + threadIdx.x;   // float4 index over all three buffers
  const float* src;
  unsigned short* dst;
  int j;
  if (i < 2097152) { src = X; dst = Xb; j = i; }
  else if (i < 2097152 + 786432) { src = W1; dst = W1b; j = i - 2097152; }
  else { src = Wo; dst = Wob; j = i - (2097152 + 786432); }
  const float4 v = ((const float4*)src)[j];
  ushort4 o;
  o.x = f2bf(v.x); o.y = f2bf(v.y); o.z = f2bf(v.z); o.w = f2bf(v.w);
  ((ushort4*)dst)[j] = o;
}

// =============== shared 128x256-tile 2-phase counted-vmcnt GEMM template ===============
// 512 threads / 8 waves (2M x 4N). BK=64 split in two 32-k units. LDS 96KB.
// Ledger (3 loads/thread/unit: A=1, B=2): prologue stages u0,u1 -> vmcnt(3)+barrier;
// each phase: read unit, stage next-step same unit (+3), MFMA, vmcnt(3) BEFORE barrier.

// ---------------- GEMM1: X[8192][1024] x W1t[3072][1024] -> Q/K direct + V transposed ----------------
__global__ __launch_bounds__(512, 2) void k_gemm_qkv(
    const unsigned short* __restrict__ A,
    const unsigned short* __restrict__ Bt,
    unsigned short* __restrict__ Qb,        // [64][2048][64]
    unsigned short* __restrict__ Kb,        // [64][2048][64]
    unsigned short* __restrict__ VTb) {     // [64][64][2048]
  __shared__ __align__(16) char Sm[98304];  // A units: 4x8KB @0; B units: 4x16KB @32768
  char* lAs = Sm;
  char* lBs = Sm + 32768;

  const int tid = threadIdx.x;            // 0..511
  const int l = tid & 63;
  const int wid = tid >> 6;               // 0..7
  const int lr = l & 15, lg = l >> 4;
  const int wr = wid >> 2, wc = wid & 3;  // 2M x 4N
  const int bm = blockIdx.x, bn = blockIdx.y;

  f32x4 acc[4][4] = {};
  const int colF = (lg * 16) ^ (((lr >> 1) & 3) << 4);

  auto STAGE_A = [&](int buf, int kt2, int uk) {
    const int row = tid >> 2;               // 0..127
    const int colb = (tid & 3) * 16;
    const int sw = ((row >> 1) & 3) << 4;
    gload_lds16((const char*)A + (size_t)(bm * 128 + row) * 2048 + kt2 * 128 + uk * 64 +
                    (colb ^ sw),
                lAs + (buf * 2 + uk) * 8192 + tid * 16);
  };
  auto STAGE_B = [&](int buf, int kt2, int uk) {
#pragma unroll
    for (int i = 0; i < 2; ++i) {
      const int idx = i * 512 + tid;        // 0..1023
      const int row = idx >> 2;             // 0..255
      const int colb = (idx & 3) * 16;
      const int sw = ((row >> 1) & 3) << 4;
      gload_lds16((const char*)Bt + (size_t)(bn * 256 + row) * 2048 + kt2 * 128 + uk * 64 +
                      (colb ^ sw),
                  lBs + (buf * 2 + uk) * 16384 + idx * 16);
    }
  };

  // prologue: u0, u1 of step 0 into buf 0; wait u0 (oldest 3), barrier
  STAGE_A(0, 0, 0); STAGE_B(0, 0, 0);
  STAGE_A(0, 0, 1); STAGE_B(0, 0, 1);
  asm volatile("s_waitcnt vmcnt(3)" ::: "memory");
  __builtin_amdgcn_s_barrier();

#pragma unroll 2
  for (int kt = 0; kt < 16; ++kt) {
    const int buf = kt & 1, nbuf = buf ^ 1;
    const int ktn = (kt + 1 < 16) ? kt + 1 : 15;   // tail: dummy restage keeps ledger uniform

#pragma unroll
    for (int uk = 0; uk < 2; ++uk) {
      bf16x8 a[4], b[4];
#pragma unroll
      for (int mf = 0; mf < 4; ++mf)
        a[mf] = *(const bf16x8*)(lAs + (buf * 2 + uk) * 8192 + (wr * 64 + mf * 16 + lr) * 64 + colF);
#pragma unroll
      for (int nf = 0; nf < 4; ++nf)
        b[nf] = *(const bf16x8*)(lBs + (buf * 2 + uk) * 16384 + (wc * 64 + nf * 16 + lr) * 64 + colF);
      STAGE_A(nbuf, ktn, uk);
      STAGE_B(nbuf, ktn, uk);
      __builtin_amdgcn_s_setprio(1);
#pragma unroll
      for (int mf = 0; mf < 4; ++mf)
#pragma unroll
        for (int nf = 0; nf < 4; ++nf)
          acc[mf][nf] = MFMA16(a[mf], b[nf], acc[mf][nf]);
      __builtin_amdgcn_s_setprio(0);
      asm volatile("s_waitcnt vmcnt(3)" ::: "memory");
      __builtin_amdgcn_s_barrier();
    }
  }

  // drain dummy restages before reusing LDS as transpose buffer
  asm volatile("s_waitcnt vmcnt(0)" ::: "memory");
  __syncthreads();

  // Epilogue. Wave col-group f0 is wholly Q, K, or V; d = nf*16+lr in all cases.
  const int f0 = bn * 256 + wc * 64;
  const int s3g = (f0 >> 6) % 3;
  const int hqg = f0 / 192;

  if (s3g != 2) {
    unsigned short* dst = (s3g == 0) ? Qb : Kb;
    const float qscale = (s3g == 0) ? 0.18033688011112042f : 1.0f;  // SCALE*log2(e) into Q
#pragma unroll
    for (int nf = 0; nf < 4; ++nf) {
      const int d = nf * 16 + lr;
#pragma unroll
      for (int mf = 0; mf < 4; ++mf) {
#pragma unroll
        for (int i = 0; i < 4; ++i) {
          const int r = bm * 128 + wr * 64 + mf * 16 + lg * 4 + i;
          const int t = r >> 2, bb2 = r & 3;
          dst[((size_t)(bb2 * 16 + hqg) * 2048 + t) * 64 + d] = f2bf(acc[mf][nf][i] * qscale);
        }
      }
    }
  } else {
    // V: per-wc transpose buffer, 128 rows x pitch 68 shorts = 17408B, stride 24576B
    // (max offset 3*24576 + 17408 = 91136 <= 98304 -- R14's 34816 stride overflowed LDS)
    unsigned short* Tb = (unsigned short*)(Sm + wc * 24576);
#pragma unroll
    for (int nf = 0; nf < 4; ++nf) {
      const int d = nf * 16 + lr;
#pragma unroll
      for (int mf = 0; mf < 4; ++mf) {
#pragma unroll
        for (int i = 0; i < 4; ++i) {
          const int rl = wr * 64 + mf * 16 + lg * 4 + i;   // 0..127
          Tb[rl * 68 + d] = f2bf(acc[mf][nf][i]);
        }
      }
    }
  }
  __syncthreads();
  if (s3g == 2) {
    // both waves of this wc (128 threads) read back & store VT[n][d][t] in 8B chunks
    unsigned short* Tb = (unsigned short*)(Sm + wc * 24576);
    const int u = wr * 64 + l;        // 0..127
    const int d = u >> 1, th = u & 1; // d 0..63, t-half
#pragma unroll
    for (int bb = 0; bb < 4; ++bb) {
      const size_t base = ((size_t)(bb * 16 + hqg) * 64 + d) * 2048 + bm * 32 + th * 16;
#pragma unroll
      for (int tq = 0; tq < 4; ++tq) {
        ushort4 pk;
        pk.x = Tb[((th * 16 + tq * 4 + 0) * 4 + bb) * 68 + d];
        pk.y = Tb[((th * 16 + tq * 4 + 1) * 4 + bb) * 68 + d];
        pk.z = Tb[((th * 16 + tq * 4 + 2) * 4 + bb) * 68 + d];
        pk.w = Tb[((th * 16 + tq * 4 + 3) * 4 + bb) * 68 + d];
        *(ushort4*)&VTb[base + tq * 4] = pk;
      }
    }
  }
}

// ---------------- GEMM4: ctx[8192][1024] x Wot[1024][1024] -> out fp32 (same template) ----------------
__global__ __launch_bounds__(512, 2) void k_gemm_out(
    const unsigned short* __restrict__ A,
    const unsigned short* __restrict__ Bt,
    float* __restrict__ C) {
  __shared__ __align__(16) char Sm[98304];
  char* lAs = Sm;
  char* lBs = Sm + 32768;

  const int tid = threadIdx.x;
  const int l = tid & 63;
  const int wid = tid >> 6;
  const int lr = l & 15, lg = l >> 4;
  const int wr = wid >> 2, wc = wid & 3;
  const int bm = blockIdx.x, bn = blockIdx.y;

  f32x4 acc[4][4] = {};
  const int colF = (lg * 16) ^ (((lr >> 1) & 3) << 4);

  auto STAGE_A = [&](int buf, int kt2, int uk) {
    const int row = tid >> 2;
    const int colb = (tid & 3) * 16;
    const int sw = ((row >> 1) & 3) << 4;
    gload_lds16((const char*)A + (size_t)(bm * 128 + row) * 2048 + kt2 * 128 + uk * 64 +
                    (colb ^ sw),
                lAs + (buf * 2 + uk) * 8192 + tid * 16);
  };
  auto STAGE_B = [&](int buf, int kt2, int uk) {
#pragma unroll
    for (int i = 0; i < 2; ++i) {
      const int idx = i * 512 + tid;
      const int row = idx >> 2;
      const int colb = (idx & 3) * 16;
      const int sw = ((row >> 1) & 3) << 4;
      gload_lds16((const char*)Bt + (size_t)(bn * 256 + row) * 2048 + kt2 * 128 + uk * 64 +
                      (colb ^ sw),
                  lBs + (buf * 2 + uk) * 16384 + idx * 16);
    }
  };

  STAGE_A(0, 0, 0); STAGE_B(0, 0, 0);
  STAGE_A(0, 0, 1); STAGE_B(0, 0, 1);
  asm volatile("s_waitcnt vmcnt(3)" ::: "memory");
  __builtin_amdgcn_s_barrier();

#pragma unroll 2
  for (int kt = 0; kt < 16; ++kt) {
    const int buf = kt & 1, nbuf = buf ^ 1;
    const int ktn = (kt + 1 < 16) ? kt + 1 : 15;

#pragma unroll
    for (int uk = 0; uk < 2; ++uk) {
      bf16x8 a[4], b[4];
#pragma unroll
      for (int mf = 0; mf < 4; ++mf)
        a[mf] = *(const bf16x8*)(lAs + (buf * 2 + uk) * 8192 + (wr * 64 + mf * 16 + lr) * 64 + colF);
#pragma unroll
      for (int nf = 0; nf < 4; ++nf)
        b[nf] = *(const bf16x8*)(lBs + (buf * 2 + uk) * 16384 + (wc * 64 + nf * 16 + lr) * 64 + colF);
      STAGE_A(nbuf, ktn, uk);
      STAGE_B(nbuf, ktn, uk);
      __builtin_amdgcn_s_setprio(1);
#pragma unroll
      for (int mf = 0; mf < 4; ++mf)
#pragma unroll
        for (int nf = 0; nf < 4; ++nf)
          acc[mf][nf] = MFMA16(a[mf], b[nf], acc[mf][nf]);
      __builtin_amdgcn_s_setprio(0);
      asm volatile("s_waitcnt vmcnt(3)" ::: "memory");
      __builtin_amdgcn_s_barrier();
    }
  }

  asm volatile("s_waitcnt vmcnt(0)" ::: "memory");   // drain tail dummy restage

#pragma unroll
  for (int mf = 0; mf < 4; ++mf)
#pragma unroll
    for (int i = 0; i < 4; ++i) {
      const int r = bm * 128 + wr * 64 + mf * 16 + lg * 4 + i;
#pragma unroll
      for (int nf = 0; nf < 4; ++nf)
        C[(size_t)r * 1024 + bn * 256 + wc * 64 + nf * 16 + lr] = acc[mf][nf][i];
    }
}

// ---------------- flash attention: q=256/block, 2-phase pipelined (R5 verified, 82us) ----------------
__global__ __launch_bounds__(256, 2) void k_attn(
    const unsigned short* __restrict__ Qb, const unsigned short* __restrict__ Kb,
    const unsigned short* __restrict__ VTb, unsigned short* __restrict__ Cx) {
  __shared__ __align__(16) unsigned short Ks[2][64 * 64];  // [s][d], xor-swizzled
  __shared__ __align__(16) unsigned short Vt[2][64 * 64];  // [d][s], xor-swizzled

  const int tid = threadIdx.x;
  const int l = tid & 63, w = tid >> 6;
  const int lq = l & 15, lg = l >> 4;
  const int n = blockIdx.x, qt = blockIdx.y;   // x = head -> same-head blocks on one XCD

  const unsigned short* Qh = Qb + (size_t)n * (2048 * 64);
  const unsigned short* Kh = Kb + (size_t)n * (2048 * 64);
  const unsigned short* Vh = VTb + (size_t)n * (64 * 2048);

  // Q fragments (B-operand of swapped QK^T): q = qt*256 + w*64 + qf*16 + lq
  bf16x8 aq[4][2];
#pragma unroll
  for (int qf = 0; qf < 4; ++qf)
#pragma unroll
    for (int kd = 0; kd < 2; ++kd)
      aq[qf][kd] = *(const bf16x8*)&Qh[(size_t)(qt * 256 + w * 64 + qf * 16 + lq) * 64 +
                                       kd * 32 + lg * 8];

  f32x4 o[4][4] = {};       // O^T acc: [df][qf]; lane: q = lq, d = df*16 + lg*4 + i
  float lsum[4] = {0.f, 0.f, 0.f, 0.f};

  char* Ksl = (char*)&Ks[0][0];
  char* Vtl = (char*)&Vt[0][0];

  auto STAGE = [&](int buf, int st) {
    const int s0 = st * 64;
#pragma unroll
    for (int it = 0; it < 2; ++it) {
      const int off = (it * 256 + tid) * 16;
      const int row = off >> 7;
      const int colb = (off & 127) ^ ((row & 7) << 4);
      gload_lds16((const char*)Kh + ((size_t)(s0 + row) << 7) + colb, Ksl + buf * 8192 + off);
      gload_lds16((const char*)Vh + ((size_t)row << 12) + (s0 << 1) + colb, Vtl + buf * 8192 + off);
    }
  };

  STAGE(0, 0);
  asm volatile("s_waitcnt vmcnt(0)" ::: "memory");
  __builtin_amdgcn_s_barrier();

#pragma unroll 2
  for (int st = 0; st < 32; ++st) {
    const int cur = st & 1;
    if (st + 1 < 32) STAGE(cur ^ 1, st + 1);   // prefetch next tile

    const char* Kc = Ksl + cur * 8192;
    const char* Vc = Vtl + cur * 8192;

    __builtin_amdgcn_s_setprio(1);
#pragma unroll
    for (int kb = 0; kb < 2; ++kb) {
      // K fragments for s-block [kb*32, kb*32+32): rows (2kb+sfl)*16 + lq
      bf16x8 kf[2][2];
#pragma unroll
      for (int sfl = 0; sfl < 2; ++sfl) {
        const int rowk = (2 * kb + sfl) * 16 + lq;
        const int sw = (rowk & 7) << 4;
        kf[sfl][0] = *(const bf16x8*)(Kc + ((rowk * 128 + lg * 16) ^ sw));
        kf[sfl][1] = *(const bf16x8*)(Kc + ((rowk * 128 + 64 + lg * 16) ^ sw));
      }

      // QK^T + softmax + in-register P->B-frag exchange, per qf
      bf16x8 pq[4];
#pragma unroll
      for (int qf = 0; qf < 4; ++qf) {
        f32x4 s0 = {0.f, 0.f, 0.f, 0.f};
        f32x4 s1 = {0.f, 0.f, 0.f, 0.f};
        s0 = MFMA16(kf[0][0], aq[qf][0], s0);
        s0 = MFMA16(kf[0][1], aq[qf][1], s0);
        s1 = MFMA16(kf[1][0], aq[qf][0], s1);
        s1 = MFMA16(kf[1][1], aq[qf][1], s1);
        float accs = 0.f;
#pragma unroll
        for (int i = 0; i < 4; ++i) {
          s0[i] = fast_exp2(s0[i]);
          s1[i] = fast_exp2(s1[i]);
          accs += s0[i] + s1[i];
        }
        lsum[qf] += accs;
        unsigned w0 = cvtpk(s0[0], s0[1]);
        unsigned w1 = cvtpk(s0[2], s0[3]);
        unsigned w2 = cvtpk(s1[0], s1[1]);
        unsigned w3 = cvtpk(s1[2], s1[3]);
        lane_swap32(w0, w2);
        lane_swap32(w1, w3);
        lane_swap16(w0, w2);
        lane_swap16(w1, w3);
        u32x4 t4 = {w0, w1, w2, w3};
        pq[qf] = __builtin_bit_cast(bf16x8, t4);
      }

      // PV for this s-block: O^T += V^T(:, kb) . P^T
#pragma unroll
      for (int df = 0; df < 4; ++df) {
        const int rowd = df * 16 + lq;
        const int sw = (rowd & 7) << 4;
        bf16x8 vf = *(const bf16x8*)(Vc + ((rowd * 128 + kb * 64 + lg * 16) ^ sw));
#pragma unroll
        for (int qf = 0; qf < 4; ++qf)
          o[df][qf] = MFMA16(vf, pq[qf], o[df][qf]);
      }
    }
    __builtin_amdgcn_s_setprio(0);

    asm volatile("s_waitcnt vmcnt(0)" ::: "memory");
    __builtin_amdgcn_s_barrier();
  }

  // epilogue: reduce lsum over lane-groups, normalize, store
  const int bb = n >> 4, h = n & 15;
#pragma unroll
  for (int qf = 0; qf < 4; ++qf) {
    float li = lsum[qf];
    li += __shfl_xor(li, 16, 64);
    li += __shfl_xor(li, 32, 64);
    const float inv = 1.0f / li;
    const int q = qt * 256 + w * 64 + qf * 16 + lq;
#pragma unroll
    for (int df = 0; df < 4; ++df) {
      ushort4 pk;
      pk.x = f2bf(o[df][qf][0] * inv);
      pk.y = f2bf(o[df][qf][1] * inv);
      pk.z = f2bf(o[df][qf][2] * inv);
      pk.w = f2bf(o[df][qf][3] * inv);
      *(ushort4*)&Cx[(size_t)(q * 4 + bb) * 1024 + h * 64 + df * 16 + lg * 4] = pk;
    }
  }
}

// ---------------- host launch ----------------
extern "C" void kernel_launch(void* const* d_in, const int* in_sizes, int n_in,
                              void* d_out, int out_size, void* d_ws, size_t ws_size,
                              hipStream_t stream) {
  const float* X = (const float*)d_in[0];    // (2048,4,1024)
  const float* W1 = (const float*)d_in[1];   // (3072,1024)
  const float* Wo = (const float*)d_in[2];   // (1024,1024)
  float* out = (float*)d_out;                // (2048,4,1024) fp32

  char* ws = (char*)d_ws;
  unsigned short* Xb  = (unsigned short*)(ws);              // 16 MB
  unsigned short* W1b = (unsigned short*)(ws + 16777216);   //  6 MB
  unsigned short* Wob = (unsigned short*)(ws + 23068672);   //  2 MB
  unsigned short* Qb  = (unsigned short*)(ws + 25165824);   // 16 MB
  unsigned short* Kb  = (unsigned short*)(ws + 41943040);   // 16 MB
  unsigned short* VTb = (unsigned short*)(ws + 58720256);   // 16 MB
  unsigned short* Cx  = (unsigned short*)(ws + 75497472);   // 16 MB

  k_cvt3<<<12288, 256, 0, stream>>>(X, W1, Wo, Xb, W1b, Wob);
  k_gemm_qkv<<<dim3(64, 12), 512, 0, stream>>>(Xb, W1b, Qb, Kb, VTb);
  k_attn<<<dim3(64, 8), 256, 0, stream>>>(Qb, Kb, VTb, Cx);
  k_gemm_out<<<dim3(64, 4), 512, 0, stream>>>(Cx, Wob, out);
}

// Round 16
// 178.049 us; speedup vs baseline: 1.1378x; 1.0030x over previous
//
#include <hip/hip_runtime.h>
#include <stdint.h>
#include <stddef.h>

// T=2048, B=4, E=1024, H=16, HD=64, N-heads = B*H = 64.
// qkv reshape: f in [0,3072) -> head hq = f/192, s3 = (f/64)%3, d = f%64, n = b*16+hq.
// Layouts: Qb,Kb = [n][t][d] bf16 ; VTb = [n][d][t] bf16 (transposed in GEMM epilogue via LDS).

typedef __attribute__((ext_vector_type(8))) short bf16x8;
typedef __attribute__((ext_vector_type(4))) float f32x4;
typedef __attribute__((ext_vector_type(4))) unsigned int u32x4;

#define MFMA16(a, b, c) __builtin_amdgcn_mfma_f32_16x16x32_bf16((a), (b), (c), 0, 0, 0)

__device__ __forceinline__ unsigned short f2bf(float f) {
  unsigned u = __builtin_bit_cast(unsigned, f);
  u += 0x7fffu + ((u >> 16) & 1u);   // RNE
  return (unsigned short)(u >> 16);
}

__device__ __forceinline__ float fast_exp2(float x) {
#if __has_builtin(__builtin_amdgcn_exp2f)
  return __builtin_amdgcn_exp2f(x);
#else
  return exp2f(x);
#endif
}

__device__ __forceinline__ unsigned cvtpk(float lo, float hi) {
  unsigned r;
  asm volatile("v_cvt_pk_bf16_f32 %0, %1, %2" : "=v"(r) : "v"(lo), "v"(hi));
  return r;
}

// a' = {a.lo32, b.lo32}, b' = {a.hi32, b.hi32}
__device__ __forceinline__ void lane_swap32(unsigned &a, unsigned &b) {
#if __has_builtin(__builtin_amdgcn_permlane32_swap)
  auto r = __builtin_amdgcn_permlane32_swap(a, b, false, false);
  a = r[0]; b = r[1];
#else
  const bool hi = (threadIdx.x & 32) != 0;
  unsigned sa = (unsigned)__shfl_xor((int)a, 32, 64);
  unsigned sb = (unsigned)__shfl_xor((int)b, 32, 64);
  unsigned na = hi ? sb : a;
  unsigned nb = hi ? b : sa;
  a = na; b = nb;
#endif
}

// a' = {a.g0, b.g0, a.g2, b.g2}, b' = {a.g1, b.g1, a.g3, b.g3} (16-lane groups)
__device__ __forceinline__ void lane_swap16(unsigned &a, unsigned &b) {
#if __has_builtin(__builtin_amdgcn_permlane16_swap)
  auto r = __builtin_amdgcn_permlane16_swap(a, b, false, false);
  a = r[0]; b = r[1];
#else
  const bool odd = (threadIdx.x & 16) != 0;
  unsigned sa = (unsigned)__shfl_xor((int)a, 16, 64);
  unsigned sb = (unsigned)__shfl_xor((int)b, 16, 64);
  unsigned na = odd ? sb : a;
  unsigned nb = odd ? b : sa;
  a = na; b = nb;
#endif
}

__device__ __forceinline__ void gload_lds16(const void* g, void* l) {
  __builtin_amdgcn_global_load_lds((const __attribute__((address_space(1))) void*)g,
                                   (__attribute__((address_space(3))) void*)l,
                                   16, 0, 0);
}

// ---------------- fused fp32 -> bf16 convert for X, W1, Wo ----------------
__global__ __launch_bounds__(256) void k_cvt3(const float* __restrict__ X,
                                              const float* __restrict__ W1,
                                              const float* __restrict__ Wo,
                                              unsigned short* __restrict__ Xb,
                                              unsigned short* __restrict__ W1b,
                                              unsigned short* __restrict__ Wob) {
  int i = blockIdx.x * 256 + threadIdx.x;   // float4 index over all three buffers
  const float* src;
  unsigned short* dst;
  int j;
  if (i < 2097152) { src = X; dst = Xb; j = i; }
  else if (i < 2097152 + 786432) { src = W1; dst = W1b; j = i - 2097152; }
  else { src = Wo; dst = Wob; j = i - (2097152 + 786432); }
  const float4 v = ((const float4*)src)[j];
  ushort4 o;
  o.x = f2bf(v.x); o.y = f2bf(v.y); o.z = f2bf(v.z); o.w = f2bf(v.w);
  ((ushort4*)dst)[j] = o;
}

// =============== shared 128x256-tile 2-phase counted-vmcnt GEMM template ===============
// 512 threads / 8 waves (2M x 4N). BK=64 split in two 32-k units. LDS 96KB.
// Ledger (3 loads/thread/unit: A=1, B=2): prologue stages u0,u1 -> vmcnt(3)+barrier;
// each phase: read unit, stage next-step same unit (+3), MFMA, vmcnt(3) BEFORE barrier.

// ---------------- GEMM1: X[8192][1024] x W1t[3072][1024] -> Q/K direct + V transposed ----------------
__global__ __launch_bounds__(512, 2) void k_gemm_qkv(
    const unsigned short* __restrict__ A,
    const unsigned short* __restrict__ Bt,
    unsigned short* __restrict__ Qb,        // [64][2048][64]
    unsigned short* __restrict__ Kb,        // [64][2048][64]
    unsigned short* __restrict__ VTb) {     // [64][64][2048]
  __shared__ __align__(16) char Sm[98304];  // A units: 4x8KB @0; B units: 4x16KB @32768
  char* lAs = Sm;
  char* lBs = Sm + 32768;

  const int tid = threadIdx.x;            // 0..511
  const int l = tid & 63;
  const int wid = tid >> 6;               // 0..7
  const int lr = l & 15, lg = l >> 4;
  const int wr = wid >> 2, wc = wid & 3;  // 2M x 4N
  const int bm = blockIdx.x, bn = blockIdx.y;

  f32x4 acc[4][4] = {};
  const int colF = (lg * 16) ^ (((lr >> 1) & 3) << 4);

  auto STAGE_A = [&](int buf, int kt2, int uk) {
    const int row = tid >> 2;               // 0..127
    const int colb = (tid & 3) * 16;
    const int sw = ((row >> 1) & 3) << 4;
    gload_lds16((const char*)A + (size_t)(bm * 128 + row) * 2048 + kt2 * 128 + uk * 64 +
                    (colb ^ sw),
                lAs + (buf * 2 + uk) * 8192 + tid * 16);
  };
  auto STAGE_B = [&](int buf, int kt2, int uk) {
#pragma unroll
    for (int i = 0; i < 2; ++i) {
      const int idx = i * 512 + tid;        // 0..1023
      const int row = idx >> 2;             // 0..255
      const int colb = (idx & 3) * 16;
      const int sw = ((row >> 1) & 3) << 4;
      gload_lds16((const char*)Bt + (size_t)(bn * 256 + row) * 2048 + kt2 * 128 + uk * 64 +
                      (colb ^ sw),
                  lBs + (buf * 2 + uk) * 16384 + idx * 16);
    }
  };

  // prologue: u0, u1 of step 0 into buf 0; wait u0 (oldest 3), barrier
  STAGE_A(0, 0, 0); STAGE_B(0, 0, 0);
  STAGE_A(0, 0, 1); STAGE_B(0, 0, 1);
  asm volatile("s_waitcnt vmcnt(3)" ::: "memory");
  __builtin_amdgcn_s_barrier();

#pragma unroll 2
  for (int kt = 0; kt < 16; ++kt) {
    const int buf = kt & 1, nbuf = buf ^ 1;
    const int ktn = (kt + 1 < 16) ? kt + 1 : 15;   // tail: dummy restage keeps ledger uniform

#pragma unroll
    for (int uk = 0; uk < 2; ++uk) {
      bf16x8 a[4], b[4];
#pragma unroll
      for (int mf = 0; mf < 4; ++mf)
        a[mf] = *(const bf16x8*)(lAs + (buf * 2 + uk) * 8192 + (wr * 64 + mf * 16 + lr) * 64 + colF);
#pragma unroll
      for (int nf = 0; nf < 4; ++nf)
        b[nf] = *(const bf16x8*)(lBs + (buf * 2 + uk) * 16384 + (wc * 64 + nf * 16 + lr) * 64 + colF);
      STAGE_A(nbuf, ktn, uk);
      STAGE_B(nbuf, ktn, uk);
      __builtin_amdgcn_s_setprio(1);
#pragma unroll
      for (int mf = 0; mf < 4; ++mf)
#pragma unroll
        for (int nf = 0; nf < 4; ++nf)
          acc[mf][nf] = MFMA16(a[mf], b[nf], acc[mf][nf]);
      __builtin_amdgcn_s_setprio(0);
      asm volatile("s_waitcnt vmcnt(3)" ::: "memory");
      __builtin_amdgcn_s_barrier();
    }
  }

  // drain dummy restages before reusing LDS as transpose buffer
  asm volatile("s_waitcnt vmcnt(0)" ::: "memory");
  __syncthreads();

  // Epilogue. Wave col-group f0 is wholly Q, K, or V; d = nf*16+lr in all cases.
  const int f0 = bn * 256 + wc * 64;
  const int s3g = (f0 >> 6) % 3;
  const int hqg = f0 / 192;

  if (s3g != 2) {
    unsigned short* dst = (s3g == 0) ? Qb : Kb;
    const float qscale = (s3g == 0) ? 0.18033688011112042f : 1.0f;  // SCALE*log2(e) into Q
#pragma unroll
    for (int nf = 0; nf < 4; ++nf) {
      const int d = nf * 16 + lr;
#pragma unroll
      for (int mf = 0; mf < 4; ++mf) {
#pragma unroll
        for (int i = 0; i < 4; ++i) {
          const int r = bm * 128 + wr * 64 + mf * 16 + lg * 4 + i;
          const int t = r >> 2, bb2 = r & 3;
          dst[((size_t)(bb2 * 16 + hqg) * 2048 + t) * 64 + d] = f2bf(acc[mf][nf][i] * qscale);
        }
      }
    }
  } else {
    // V: per-wc transpose buffer, 128 rows x pitch 68 shorts = 17408B, stride 24576B
    unsigned short* Tb = (unsigned short*)(Sm + wc * 24576);
#pragma unroll
    for (int nf = 0; nf < 4; ++nf) {
      const int d = nf * 16 + lr;
#pragma unroll
      for (int mf = 0; mf < 4; ++mf) {
#pragma unroll
        for (int i = 0; i < 4; ++i) {
          const int rl = wr * 64 + mf * 16 + lg * 4 + i;   // 0..127
          Tb[rl * 68 + d] = f2bf(acc[mf][nf][i]);
        }
      }
    }
  }
  __syncthreads();
  if (s3g == 2) {
    // both waves of this wc (128 threads) read back & store VT[n][d][t] in 8B chunks
    unsigned short* Tb = (unsigned short*)(Sm + wc * 24576);
    const int u = wr * 64 + l;        // 0..127
    const int d = u >> 1, th = u & 1; // d 0..63, t-half
#pragma unroll
    for (int bb = 0; bb < 4; ++bb) {
      const size_t base = ((size_t)(bb * 16 + hqg) * 64 + d) * 2048 + bm * 32 + th * 16;
#pragma unroll
      for (int tq = 0; tq < 4; ++tq) {
        ushort4 pk;
        pk.x = Tb[((th * 16 + tq * 4 + 0) * 4 + bb) * 68 + d];
        pk.y = Tb[((th * 16 + tq * 4 + 1) * 4 + bb) * 68 + d];
        pk.z = Tb[((th * 16 + tq * 4 + 2) * 4 + bb) * 68 + d];
        pk.w = Tb[((th * 16 + tq * 4 + 3) * 4 + bb) * 68 + d];
        *(ushort4*)&VTb[base + tq * 4] = pk;
      }
    }
  }
}

// ---------------- GEMM4: ctx[8192][1024] x Wot[1024][1024] -> out fp32 (same template) ----------------
__global__ __launch_bounds__(512, 2) void k_gemm_out(
    const unsigned short* __restrict__ A,
    const unsigned short* __restrict__ Bt,
    float* __restrict__ C) {
  __shared__ __align__(16) char Sm[98304];
  char* lAs = Sm;
  char* lBs = Sm + 32768;

  const int tid = threadIdx.x;
  const int l = tid & 63;
  const int wid = tid >> 6;
  const int lr = l & 15, lg = l >> 4;
  const int wr = wid >> 2, wc = wid & 3;
  const int bm = blockIdx.x, bn = blockIdx.y;

  f32x4 acc[4][4] = {};
  const int colF = (lg * 16) ^ (((lr >> 1) & 3) << 4);

  auto STAGE_A = [&](int buf, int kt2, int uk) {
    const int row = tid >> 2;
    const int colb = (tid & 3) * 16;
    const int sw = ((row >> 1) & 3) << 4;
    gload_lds16((const char*)A + (size_t)(bm * 128 + row) * 2048 + kt2 * 128 + uk * 64 +
                    (colb ^ sw),
                lAs + (buf * 2 + uk) * 8192 + tid * 16);
  };
  auto STAGE_B = [&](int buf, int kt2, int uk) {
#pragma unroll
    for (int i = 0; i < 2; ++i) {
      const int idx = i * 512 + tid;
      const int row = idx >> 2;
      const int colb = (idx & 3) * 16;
      const int sw = ((row >> 1) & 3) << 4;
      gload_lds16((const char*)Bt + (size_t)(bn * 256 + row) * 2048 + kt2 * 128 + uk * 64 +
                      (colb ^ sw),
                  lBs + (buf * 2 + uk) * 16384 + idx * 16);
    }
  };

  STAGE_A(0, 0, 0); STAGE_B(0, 0, 0);
  STAGE_A(0, 0, 1); STAGE_B(0, 0, 1);
  asm volatile("s_waitcnt vmcnt(3)" ::: "memory");
  __builtin_amdgcn_s_barrier();

#pragma unroll 2
  for (int kt = 0; kt < 16; ++kt) {
    const int buf = kt & 1, nbuf = buf ^ 1;
    const int ktn = (kt + 1 < 16) ? kt + 1 : 15;

#pragma unroll
    for (int uk = 0; uk < 2; ++uk) {
      bf16x8 a[4], b[4];
#pragma unroll
      for (int mf = 0; mf < 4; ++mf)
        a[mf] = *(const bf16x8*)(lAs + (buf * 2 + uk) * 8192 + (wr * 64 + mf * 16 + lr) * 64 + colF);
#pragma unroll
      for (int nf = 0; nf < 4; ++nf)
        b[nf] = *(const bf16x8*)(lBs + (buf * 2 + uk) * 16384 + (wc * 64 + nf * 16 + lr) * 64 + colF);
      STAGE_A(nbuf, ktn, uk);
      STAGE_B(nbuf, ktn, uk);
      __builtin_amdgcn_s_setprio(1);
#pragma unroll
      for (int mf = 0; mf < 4; ++mf)
#pragma unroll
        for (int nf = 0; nf < 4; ++nf)
          acc[mf][nf] = MFMA16(a[mf], b[nf], acc[mf][nf]);
      __builtin_amdgcn_s_setprio(0);
      asm volatile("s_waitcnt vmcnt(3)" ::: "memory");
      __builtin_amdgcn_s_barrier();
    }
  }

  asm volatile("s_waitcnt vmcnt(0)" ::: "memory");   // drain tail dummy restage

#pragma unroll
  for (int mf = 0; mf < 4; ++mf)
#pragma unroll
    for (int i = 0; i < 4; ++i) {
      const int r = bm * 128 + wr * 64 + mf * 16 + lg * 4 + i;
#pragma unroll
      for (int nf = 0; nf < 4; ++nf)
        C[(size_t)r * 1024 + bn * 256 + wc * 64 + nf * 16 + lr] = acc[mf][nf][i];
    }
}

// ---------------- flash attention: q=256/block, 2-phase pipelined, MFMA-computed lsum ----------------
__global__ __launch_bounds__(256, 2) void k_attn(
    const unsigned short* __restrict__ Qb, const unsigned short* __restrict__ Kb,
    const unsigned short* __restrict__ VTb, unsigned short* __restrict__ Cx) {
  __shared__ __align__(16) unsigned short Ks[2][64 * 64];  // [s][d], xor-swizzled
  __shared__ __align__(16) unsigned short Vt[2][64 * 64];  // [d][s], xor-swizzled

  const int tid = threadIdx.x;
  const int l = tid & 63, w = tid >> 6;
  const int lq = l & 15, lg = l >> 4;
  const int n = blockIdx.x, qt = blockIdx.y;   // x = head -> same-head blocks on one XCD

  const unsigned short* Qh = Qb + (size_t)n * (2048 * 64);
  const unsigned short* Kh = Kb + (size_t)n * (2048 * 64);
  const unsigned short* Vh = VTb + (size_t)n * (64 * 2048);

  // Q fragments (B-operand of swapped QK^T): q = qt*256 + w*64 + qf*16 + lq
  bf16x8 aq[4][2];
#pragma unroll
  for (int qf = 0; qf < 4; ++qf)
#pragma unroll
    for (int kd = 0; kd < 2; ++kd)
      aq[qf][kd] = *(const bf16x8*)&Qh[(size_t)(qt * 256 + w * 64 + qf * 16 + lq) * 64 +
                                       kd * 32 + lg * 8];

  f32x4 o[4][4] = {};       // O^T acc: [df][qf]; lane: q = lq, d = df*16 + lg*4 + i
  f32x4 osum[4] = {};       // denominator acc via ones-row MFMA: all i equal sum_k P[k][q=lq]

  // all-ones bf16 fragment (1.0 = 0x3F80)
  const short ONE = (short)0x3F80;
  const bf16x8 aones = {ONE, ONE, ONE, ONE, ONE, ONE, ONE, ONE};

  char* Ksl = (char*)&Ks[0][0];
  char* Vtl = (char*)&Vt[0][0];

  auto STAGE = [&](int buf, int st) {
    const int s0 = st * 64;
#pragma unroll
    for (int it = 0; it < 2; ++it) {
      const int off = (it * 256 + tid) * 16;
      const int row = off >> 7;
      const int colb = (off & 127) ^ ((row & 7) << 4);
      gload_lds16((const char*)Kh + ((size_t)(s0 + row) << 7) + colb, Ksl + buf * 8192 + off);
      gload_lds16((const char*)Vh + ((size_t)row << 12) + (s0 << 1) + colb, Vtl + buf * 8192 + off);
    }
  };

  STAGE(0, 0);
  asm volatile("s_waitcnt vmcnt(0)" ::: "memory");
  __builtin_amdgcn_s_barrier();

#pragma unroll 2
  for (int st = 0; st < 32; ++st) {
    const int cur = st & 1;
    if (st + 1 < 32) STAGE(cur ^ 1, st + 1);   // prefetch next tile

    const char* Kc = Ksl + cur * 8192;
    const char* Vc = Vtl + cur * 8192;

    __builtin_amdgcn_s_setprio(1);
#pragma unroll
    for (int kb = 0; kb < 2; ++kb) {
      // K fragments for s-block [kb*32, kb*32+32): rows (2kb+sfl)*16 + lq
      bf16x8 kf[2][2];
#pragma unroll
      for (int sfl = 0; sfl < 2; ++sfl) {
        const int rowk = (2 * kb + sfl) * 16 + lq;
        const int sw = (rowk & 7) << 4;
        kf[sfl][0] = *(const bf16x8*)(Kc + ((rowk * 128 + lg * 16) ^ sw));
        kf[sfl][1] = *(const bf16x8*)(Kc + ((rowk * 128 + 64 + lg * 16) ^ sw));
      }

      // QK^T + exp2 + in-register P->B-frag exchange, per qf (no VALU sum: MFMA ones-row)
      bf16x8 pq[4];
#pragma unroll
      for (int qf = 0; qf < 4; ++qf) {
        f32x4 s0 = {0.f, 0.f, 0.f, 0.f};
        f32x4 s1 = {0.f, 0.f, 0.f, 0.f};
        s0 = MFMA16(kf[0][0], aq[qf][0], s0);
        s0 = MFMA16(kf[0][1], aq[qf][1], s0);
        s1 = MFMA16(kf[1][0], aq[qf][0], s1);
        s1 = MFMA16(kf[1][1], aq[qf][1], s1);
#pragma unroll
        for (int i = 0; i < 4; ++i) {
          s0[i] = fast_exp2(s0[i]);
          s1[i] = fast_exp2(s1[i]);
        }
        unsigned w0 = cvtpk(s0[0], s0[1]);
        unsigned w1 = cvtpk(s0[2], s0[3]);
        unsigned w2 = cvtpk(s1[0], s1[1]);
        unsigned w3 = cvtpk(s1[2], s1[3]);
        lane_swap32(w0, w2);
        lane_swap32(w1, w3);
        lane_swap16(w0, w2);
        lane_swap16(w1, w3);
        u32x4 t4 = {w0, w1, w2, w3};
        pq[qf] = __builtin_bit_cast(bf16x8, t4);
        // denominator: every output row = sum_k P[k][q]; accumulate once per (qf, kb)
        osum[qf] = MFMA16(aones, pq[qf], osum[qf]);
      }

      // PV for this s-block: O^T += V^T(:, kb) . P^T
#pragma unroll
      for (int df = 0; df < 4; ++df) {
        const int rowd = df * 16 + lq;
        const int sw = (rowd & 7) << 4;
        bf16x8 vf = *(const bf16x8*)(Vc + ((rowd * 128 + kb * 64 + lg * 16) ^ sw));
#pragma unroll
        for (int qf = 0; qf < 4; ++qf)
          o[df][qf] = MFMA16(vf, pq[qf], o[df][qf]);
      }
    }
    __builtin_amdgcn_s_setprio(0);

    asm volatile("s_waitcnt vmcnt(0)" ::: "memory");
    __builtin_amdgcn_s_barrier();
  }

  // epilogue: lsum is lane-local now (osum rows all equal) -> no cross-lane reduce
  const int bb = n >> 4, h = n & 15;
#pragma unroll
  for (int qf = 0; qf < 4; ++qf) {
    const float inv = 1.0f / osum[qf][0];
    const int q = qt * 256 + w * 64 + qf * 16 + lq;
#pragma unroll
    for (int df = 0; df < 4; ++df) {
      ushort4 pk;
      pk.x = f2bf(o[df][qf][0] * inv);
      pk.y = f2bf(o[df][qf][1] * inv);
      pk.z = f2bf(o[df][qf][2] * inv);
      pk.w = f2bf(o[df][qf][3] * inv);
      *(ushort4*)&Cx[(size_t)(q * 4 + bb) * 1024 + h * 64 + df * 16 + lg * 4] = pk;
    }
  }
}

// ---------------- host launch ----------------
extern "C" void kernel_launch(void* const* d_in, const int* in_sizes, int n_in,
                              void* d_out, int out_size, void* d_ws, size_t ws_size,
                              hipStream_t stream) {
  const float* X = (const float*)d_in[0];    // (2048,4,1024)
  const float* W1 = (const float*)d_in[1];   // (3072,1024)
  const float* Wo = (const float*)d_in[2];   // (1024,1024)
  float* out = (float*)d_out;                // (2048,4,1024) fp32

  char* ws = (char*)d_ws;
  unsigned short* Xb  = (unsigned short*)(ws);              // 16 MB
  unsigned short* W1b = (unsigned short*)(ws + 16777216);   //  6 MB
  unsigned short* Wob = (unsigned short*)(ws + 23068672);   //  2 MB
  unsigned short* Qb  = (unsigned short*)(ws + 25165824);   // 16 MB
  unsigned short* Kb  = (unsigned short*)(ws + 41943040);   // 16 MB
  unsigned short* VTb = (unsigned short*)(ws + 58720256);   // 16 MB
  unsigned short* Cx  = (unsigned short*)(ws + 75497472);   // 16 MB

  k_cvt3<<<12288, 256, 0, stream>>>(X, W1, Wo, Xb, W1b, Wob);
  k_gemm_qkv<<<dim3(64, 12), 512, 0, stream>>>(Xb, W1b, Qb, Kb, VTb);
  k_attn<<<dim3(64, 8), 256, 0, stream>>>(Qb, Kb, VTb, Cx);
  k_gemm_out<<<dim3(64, 4), 512, 0, stream>>>(Cx, Wob, out);
}

// Round 17
// 176.859 us; speedup vs baseline: 1.1455x; 1.0067x over previous
//
#include <hip/hip_runtime.h>
#include <stdint.h>
#include <stddef.h>

// T=2048, B=4, E=1024, H=16, HD=64, N-heads = B*H = 64.
// qkv reshape: f in [0,3072) -> head hq = f/192, s3 = (f/64)%3, d = f%64, n = b*16+hq.
// Layouts: Qb,Kb = [n][t][d] bf16 ; VTb = [n][d][t] bf16 (transposed in GEMM epilogue via LDS).

typedef __attribute__((ext_vector_type(8))) short bf16x8;
typedef __attribute__((ext_vector_type(4))) float f32x4;
typedef __attribute__((ext_vector_type(4))) unsigned int u32x4;

#define MFMA16(a, b, c) __builtin_amdgcn_mfma_f32_16x16x32_bf16((a), (b), (c), 0, 0, 0)

__device__ __forceinline__ unsigned short f2bf(float f) {
  unsigned u = __builtin_bit_cast(unsigned, f);
  u += 0x7fffu + ((u >> 16) & 1u);   // RNE
  return (unsigned short)(u >> 16);
}

__device__ __forceinline__ float fast_exp2(float x) {
#if __has_builtin(__builtin_amdgcn_exp2f)
  return __builtin_amdgcn_exp2f(x);
#else
  return exp2f(x);
#endif
}

__device__ __forceinline__ unsigned cvtpk(float lo, float hi) {
  unsigned r;
  asm volatile("v_cvt_pk_bf16_f32 %0, %1, %2" : "=v"(r) : "v"(lo), "v"(hi));
  return r;
}

// a' = {a.lo32, b.lo32}, b' = {a.hi32, b.hi32}
__device__ __forceinline__ void lane_swap32(unsigned &a, unsigned &b) {
#if __has_builtin(__builtin_amdgcn_permlane32_swap)
  auto r = __builtin_amdgcn_permlane32_swap(a, b, false, false);
  a = r[0]; b = r[1];
#else
  const bool hi = (threadIdx.x & 32) != 0;
  unsigned sa = (unsigned)__shfl_xor((int)a, 32, 64);
  unsigned sb = (unsigned)__shfl_xor((int)b, 32, 64);
  unsigned na = hi ? sb : a;
  unsigned nb = hi ? b : sa;
  a = na; b = nb;
#endif
}

// a' = {a.g0, b.g0, a.g2, b.g2}, b' = {a.g1, b.g1, a.g3, b.g3} (16-lane groups)
__device__ __forceinline__ void lane_swap16(unsigned &a, unsigned &b) {
#if __has_builtin(__builtin_amdgcn_permlane16_swap)
  auto r = __builtin_amdgcn_permlane16_swap(a, b, false, false);
  a = r[0]; b = r[1];
#else
  const bool odd = (threadIdx.x & 16) != 0;
  unsigned sa = (unsigned)__shfl_xor((int)a, 16, 64);
  unsigned sb = (unsigned)__shfl_xor((int)b, 16, 64);
  unsigned na = odd ? sb : a;
  unsigned nb = odd ? b : sa;
  a = na; b = nb;
#endif
}

__device__ __forceinline__ void gload_lds16(const void* g, void* l) {
  __builtin_amdgcn_global_load_lds((const __attribute__((address_space(1))) void*)g,
                                   (__attribute__((address_space(3))) void*)l,
                                   16, 0, 0);
}

// ---------------- fused fp32 -> bf16 convert for X, W1, Wo ----------------
__global__ __launch_bounds__(256) void k_cvt3(const float* __restrict__ X,
                                              const float* __restrict__ W1,
                                              const float* __restrict__ Wo,
                                              unsigned short* __restrict__ Xb,
                                              unsigned short* __restrict__ W1b,
                                              unsigned short* __restrict__ Wob) {
  int i = blockIdx.x * 256 + threadIdx.x;   // float4 index over all three buffers
  const float* src;
  unsigned short* dst;
  int j;
  if (i < 2097152) { src = X; dst = Xb; j = i; }
  else if (i < 2097152 + 786432) { src = W1; dst = W1b; j = i - 2097152; }
  else { src = Wo; dst = Wob; j = i - (2097152 + 786432); }
  const float4 v = ((const float4*)src)[j];
  ushort4 o;
  o.x = f2bf(v.x); o.y = f2bf(v.y); o.z = f2bf(v.z); o.w = f2bf(v.w);
  ((ushort4*)dst)[j] = o;
}

// =============== shared 128x256-tile 2-phase counted-vmcnt GEMM template ===============
// 512 threads / 8 waves (2M x 4N). BK=64 split in two 32-k units. LDS 96KB.
// Ledger (3 loads/thread/unit: A=1, B=2): prologue stages u0,u1 -> vmcnt(3)+barrier;
// each phase: read unit, stage next-step same unit (+3), MFMA, vmcnt(3) BEFORE barrier.

// ---------------- GEMM1: X[8192][1024] x W1t[3072][1024] -> Q/K direct + V transposed ----------------
__global__ __launch_bounds__(512, 2) void k_gemm_qkv(
    const unsigned short* __restrict__ A,
    const unsigned short* __restrict__ Bt,
    unsigned short* __restrict__ Qb,        // [64][2048][64]
    unsigned short* __restrict__ Kb,        // [64][2048][64]
    unsigned short* __restrict__ VTb) {     // [64][64][2048]
  __shared__ __align__(16) char Sm[98304];  // A units: 4x8KB @0; B units: 4x16KB @32768
  char* lAs = Sm;
  char* lBs = Sm + 32768;

  const int tid = threadIdx.x;            // 0..511
  const int l = tid & 63;
  const int wid = tid >> 6;               // 0..7
  const int lr = l & 15, lg = l >> 4;
  const int wr = wid >> 2, wc = wid & 3;  // 2M x 4N
  const int bm = blockIdx.x, bn = blockIdx.y;

  f32x4 acc[4][4] = {};
  const int colF = (lg * 16) ^ (((lr >> 1) & 3) << 4);

  auto STAGE_A = [&](int buf, int kt2, int uk) {
    const int row = tid >> 2;               // 0..127
    const int colb = (tid & 3) * 16;
    const int sw = ((row >> 1) & 3) << 4;
    gload_lds16((const char*)A + (size_t)(bm * 128 + row) * 2048 + kt2 * 128 + uk * 64 +
                    (colb ^ sw),
                lAs + (buf * 2 + uk) * 8192 + tid * 16);
  };
  auto STAGE_B = [&](int buf, int kt2, int uk) {
#pragma unroll
    for (int i = 0; i < 2; ++i) {
      const int idx = i * 512 + tid;        // 0..1023
      const int row = idx >> 2;             // 0..255
      const int colb = (idx & 3) * 16;
      const int sw = ((row >> 1) & 3) << 4;
      gload_lds16((const char*)Bt + (size_t)(bn * 256 + row) * 2048 + kt2 * 128 + uk * 64 +
                      (colb ^ sw),
                  lBs + (buf * 2 + uk) * 16384 + idx * 16);
    }
  };

  // prologue: u0, u1 of step 0 into buf 0; wait u0 (oldest 3), barrier
  STAGE_A(0, 0, 0); STAGE_B(0, 0, 0);
  STAGE_A(0, 0, 1); STAGE_B(0, 0, 1);
  asm volatile("s_waitcnt vmcnt(3)" ::: "memory");
  __builtin_amdgcn_s_barrier();

#pragma unroll 2
  for (int kt = 0; kt < 16; ++kt) {
    const int buf = kt & 1, nbuf = buf ^ 1;
    const int ktn = (kt + 1 < 16) ? kt + 1 : 15;   // tail: dummy restage keeps ledger uniform

#pragma unroll
    for (int uk = 0; uk < 2; ++uk) {
      bf16x8 a[4], b[4];
#pragma unroll
      for (int mf = 0; mf < 4; ++mf)
        a[mf] = *(const bf16x8*)(lAs + (buf * 2 + uk) * 8192 + (wr * 64 + mf * 16 + lr) * 64 + colF);
#pragma unroll
      for (int nf = 0; nf < 4; ++nf)
        b[nf] = *(const bf16x8*)(lBs + (buf * 2 + uk) * 16384 + (wc * 64 + nf * 16 + lr) * 64 + colF);
      STAGE_A(nbuf, ktn, uk);
      STAGE_B(nbuf, ktn, uk);
      __builtin_amdgcn_s_setprio(1);
#pragma unroll
      for (int mf = 0; mf < 4; ++mf)
#pragma unroll
        for (int nf = 0; nf < 4; ++nf)
          acc[mf][nf] = MFMA16(a[mf], b[nf], acc[mf][nf]);
      __builtin_amdgcn_s_setprio(0);
      asm volatile("s_waitcnt vmcnt(3)" ::: "memory");
      __builtin_amdgcn_s_barrier();
    }
  }

  // drain dummy restages before reusing LDS as transpose buffer
  asm volatile("s_waitcnt vmcnt(0)" ::: "memory");
  __syncthreads();

  // Epilogue. Wave col-group f0 is wholly Q, K, or V; d = nf*16+lr in all cases.
  const int f0 = bn * 256 + wc * 64;
  const int s3g = (f0 >> 6) % 3;
  const int hqg = f0 / 192;

  if (s3g != 2) {
    unsigned short* dst = (s3g == 0) ? Qb : Kb;
    const float qscale = (s3g == 0) ? 0.18033688011112042f : 1.0f;  // SCALE*log2(e) into Q
#pragma unroll
    for (int nf = 0; nf < 4; ++nf) {
      const int d = nf * 16 + lr;
#pragma unroll
      for (int mf = 0; mf < 4; ++mf) {
#pragma unroll
        for (int i = 0; i < 4; ++i) {
          const int r = bm * 128 + wr * 64 + mf * 16 + lg * 4 + i;
          const int t = r >> 2, bb2 = r & 3;
          dst[((size_t)(bb2 * 16 + hqg) * 2048 + t) * 64 + d] = f2bf(acc[mf][nf][i] * qscale);
        }
      }
    }
  } else {
    // V: per-wc transpose buffer, 128 rows x pitch 68 shorts = 17408B, stride 24576B
    unsigned short* Tb = (unsigned short*)(Sm + wc * 24576);
#pragma unroll
    for (int nf = 0; nf < 4; ++nf) {
      const int d = nf * 16 + lr;
#pragma unroll
      for (int mf = 0; mf < 4; ++mf) {
#pragma unroll
        for (int i = 0; i < 4; ++i) {
          const int rl = wr * 64 + mf * 16 + lg * 4 + i;   // 0..127
          Tb[rl * 68 + d] = f2bf(acc[mf][nf][i]);
        }
      }
    }
  }
  __syncthreads();
  if (s3g == 2) {
    // both waves of this wc (128 threads) read back & store VT[n][d][t] in 8B chunks
    unsigned short* Tb = (unsigned short*)(Sm + wc * 24576);
    const int u = wr * 64 + l;        // 0..127
    const int d = u >> 1, th = u & 1; // d 0..63, t-half
#pragma unroll
    for (int bb = 0; bb < 4; ++bb) {
      const size_t base = ((size_t)(bb * 16 + hqg) * 64 + d) * 2048 + bm * 32 + th * 16;
#pragma unroll
      for (int tq = 0; tq < 4; ++tq) {
        ushort4 pk;
        pk.x = Tb[((th * 16 + tq * 4 + 0) * 4 + bb) * 68 + d];
        pk.y = Tb[((th * 16 + tq * 4 + 1) * 4 + bb) * 68 + d];
        pk.z = Tb[((th * 16 + tq * 4 + 2) * 4 + bb) * 68 + d];
        pk.w = Tb[((th * 16 + tq * 4 + 3) * 4 + bb) * 68 + d];
        *(ushort4*)&VTb[base + tq * 4] = pk;
      }
    }
  }
}

// ---------------- GEMM4: ctx[8192][1024] x Wot[1024][1024] -> out fp32 (same template) ----------------
__global__ __launch_bounds__(512, 2) void k_gemm_out(
    const unsigned short* __restrict__ A,
    const unsigned short* __restrict__ Bt,
    float* __restrict__ C) {
  __shared__ __align__(16) char Sm[98304];
  char* lAs = Sm;
  char* lBs = Sm + 32768;

  const int tid = threadIdx.x;
  const int l = tid & 63;
  const int wid = tid >> 6;
  const int lr = l & 15, lg = l >> 4;
  const int wr = wid >> 2, wc = wid & 3;
  const int bm = blockIdx.x, bn = blockIdx.y;

  f32x4 acc[4][4] = {};
  const int colF = (lg * 16) ^ (((lr >> 1) & 3) << 4);

  auto STAGE_A = [&](int buf, int kt2, int uk) {
    const int row = tid >> 2;
    const int colb = (tid & 3) * 16;
    const int sw = ((row >> 1) & 3) << 4;
    gload_lds16((const char*)A + (size_t)(bm * 128 + row) * 2048 + kt2 * 128 + uk * 64 +
                    (colb ^ sw),
                lAs + (buf * 2 + uk) * 8192 + tid * 16);
  };
  auto STAGE_B = [&](int buf, int kt2, int uk) {
#pragma unroll
    for (int i = 0; i < 2; ++i) {
      const int idx = i * 512 + tid;
      const int row = idx >> 2;
      const int colb = (idx & 3) * 16;
      const int sw = ((row >> 1) & 3) << 4;
      gload_lds16((const char*)Bt + (size_t)(bn * 256 + row) * 2048 + kt2 * 128 + uk * 64 +
                      (colb ^ sw),
                  lBs + (buf * 2 + uk) * 16384 + idx * 16);
    }
  };

  STAGE_A(0, 0, 0); STAGE_B(0, 0, 0);
  STAGE_A(0, 0, 1); STAGE_B(0, 0, 1);
  asm volatile("s_waitcnt vmcnt(3)" ::: "memory");
  __builtin_amdgcn_s_barrier();

#pragma unroll 2
  for (int kt = 0; kt < 16; ++kt) {
    const int buf = kt & 1, nbuf = buf ^ 1;
    const int ktn = (kt + 1 < 16) ? kt + 1 : 15;

#pragma unroll
    for (int uk = 0; uk < 2; ++uk) {
      bf16x8 a[4], b[4];
#pragma unroll
      for (int mf = 0; mf < 4; ++mf)
        a[mf] = *(const bf16x8*)(lAs + (buf * 2 + uk) * 8192 + (wr * 64 + mf * 16 + lr) * 64 + colF);
#pragma unroll
      for (int nf = 0; nf < 4; ++nf)
        b[nf] = *(const bf16x8*)(lBs + (buf * 2 + uk) * 16384 + (wc * 64 + nf * 16 + lr) * 64 + colF);
      STAGE_A(nbuf, ktn, uk);
      STAGE_B(nbuf, ktn, uk);
      __builtin_amdgcn_s_setprio(1);
#pragma unroll
      for (int mf = 0; mf < 4; ++mf)
#pragma unroll
        for (int nf = 0; nf < 4; ++nf)
          acc[mf][nf] = MFMA16(a[mf], b[nf], acc[mf][nf]);
      __builtin_amdgcn_s_setprio(0);
      asm volatile("s_waitcnt vmcnt(3)" ::: "memory");
      __builtin_amdgcn_s_barrier();
    }
  }

  asm volatile("s_waitcnt vmcnt(0)" ::: "memory");   // drain tail dummy restage

#pragma unroll
  for (int mf = 0; mf < 4; ++mf)
#pragma unroll
    for (int i = 0; i < 4; ++i) {
      const int r = bm * 128 + wr * 64 + mf * 16 + lg * 4 + i;
#pragma unroll
      for (int nf = 0; nf < 4; ++nf)
        C[(size_t)r * 1024 + bn * 256 + wc * 64 + nf * 16 + lr] = acc[mf][nf][i];
    }
}

// ---------------- flash attention: q=256/block, KVBLK=128 double-buffered (half the barriers) ----------------
__global__ __launch_bounds__(256, 2) void k_attn(
    const unsigned short* __restrict__ Qb, const unsigned short* __restrict__ Kb,
    const unsigned short* __restrict__ VTb, unsigned short* __restrict__ Cx) {
  __shared__ __align__(16) unsigned short Ks[2][128 * 64];  // [s][d] 128B rows, swz (row&7)<<4
  __shared__ __align__(16) unsigned short Vt[2][64 * 128];  // [d][s] 256B rows, swz (row&7)<<4

  const int tid = threadIdx.x;
  const int l = tid & 63, w = tid >> 6;
  const int lq = l & 15, lg = l >> 4;
  const int n = blockIdx.x, qt = blockIdx.y;   // x = head -> same-head blocks on one XCD

  const unsigned short* Qh = Qb + (size_t)n * (2048 * 64);
  const unsigned short* Kh = Kb + (size_t)n * (2048 * 64);
  const unsigned short* Vh = VTb + (size_t)n * (64 * 2048);

  // Q fragments (B-operand of swapped QK^T): q = qt*256 + w*64 + qf*16 + lq
  bf16x8 aq[4][2];
#pragma unroll
  for (int qf = 0; qf < 4; ++qf)
#pragma unroll
    for (int kd = 0; kd < 2; ++kd)
      aq[qf][kd] = *(const bf16x8*)&Qh[(size_t)(qt * 256 + w * 64 + qf * 16 + lq) * 64 +
                                       kd * 32 + lg * 8];

  f32x4 o[4][4] = {};       // O^T acc: [df][qf]; lane: q = lq, d = df*16 + lg*4 + i
  f32x4 osum[4] = {};       // denominator acc via ones-row MFMA

  const short ONE = (short)0x3F80;
  const bf16x8 aones = {ONE, ONE, ONE, ONE, ONE, ONE, ONE, ONE};

  char* Ksl = (char*)&Ks[0][0];
  char* Vtl = (char*)&Vt[0][0];

  // stage one 128-key tile: K 16KB + V^T 16KB (8 loads/thread)
  auto STAGE = [&](int buf, int st) {
    const int s0 = st * 128;
#pragma unroll
    for (int it = 0; it < 4; ++it) {
      const int off = (it * 256 + tid) * 16;
      const int row = off >> 7;                               // 0..127 (key)
      const int colb = (off & 127) ^ ((row & 7) << 4);
      gload_lds16((const char*)Kh + ((size_t)(s0 + row) << 7) + colb, Ksl + buf * 16384 + off);
    }
#pragma unroll
    for (int it = 0; it < 4; ++it) {
      const int off = (it * 256 + tid) * 16;
      const int row = off >> 8;                               // 0..63 (d)
      const int colb = (off & 255) ^ ((row & 7) << 4);
      gload_lds16((const char*)Vh + ((size_t)row << 12) + (s0 << 1) + colb, Vtl + buf * 16384 + off);
    }
  };

  STAGE(0, 0);
  asm volatile("s_waitcnt vmcnt(0)" ::: "memory");
  __builtin_amdgcn_s_barrier();

#pragma unroll 2
  for (int st = 0; st < 16; ++st) {
    const int cur = st & 1;
    if (st + 1 < 16) STAGE(cur ^ 1, st + 1);   // prefetch next 128-key tile

    const char* Kc = Ksl + cur * 16384;
    const char* Vc = Vtl + cur * 16384;

    __builtin_amdgcn_s_setprio(1);
#pragma unroll
    for (int kb = 0; kb < 4; ++kb) {
      // K fragments for s-block [kb*32, kb*32+32): rows kb*32 + sfl*16 + lq
      bf16x8 kf[2][2];
#pragma unroll
      for (int sfl = 0; sfl < 2; ++sfl) {
        const int rowk = kb * 32 + sfl * 16 + lq;
        const int sw = (rowk & 7) << 4;
        kf[sfl][0] = *(const bf16x8*)(Kc + ((rowk * 128 + lg * 16) ^ sw));
        kf[sfl][1] = *(const bf16x8*)(Kc + ((rowk * 128 + 64 + lg * 16) ^ sw));
      }

      // QK^T + exp2 + in-register P->B-frag exchange, per qf
      bf16x8 pq[4];
#pragma unroll
      for (int qf = 0; qf < 4; ++qf) {
        f32x4 s0 = {0.f, 0.f, 0.f, 0.f};
        f32x4 s1 = {0.f, 0.f, 0.f, 0.f};
        s0 = MFMA16(kf[0][0], aq[qf][0], s0);
        s0 = MFMA16(kf[0][1], aq[qf][1], s0);
        s1 = MFMA16(kf[1][0], aq[qf][0], s1);
        s1 = MFMA16(kf[1][1], aq[qf][1], s1);
#pragma unroll
        for (int i = 0; i < 4; ++i) {
          s0[i] = fast_exp2(s0[i]);
          s1[i] = fast_exp2(s1[i]);
        }
        unsigned w0 = cvtpk(s0[0], s0[1]);
        unsigned w1 = cvtpk(s0[2], s0[3]);
        unsigned w2 = cvtpk(s1[0], s1[1]);
        unsigned w3 = cvtpk(s1[2], s1[3]);
        lane_swap32(w0, w2);
        lane_swap32(w1, w3);
        lane_swap16(w0, w2);
        lane_swap16(w1, w3);
        u32x4 t4 = {w0, w1, w2, w3};
        pq[qf] = __builtin_bit_cast(bf16x8, t4);
        osum[qf] = MFMA16(aones, pq[qf], osum[qf]);   // denominator via matrix pipe
      }

      // PV for this s-block: O^T += V^T(:, kb) . P^T  (V rows 256B)
#pragma unroll
      for (int df = 0; df < 4; ++df) {
        const int rowd = df * 16 + lq;
        const int sw = (rowd & 7) << 4;
        bf16x8 vf = *(const bf16x8*)(Vc + rowd * 256 + ((kb * 64 + lg * 16) ^ sw));
#pragma unroll
        for (int qf = 0; qf < 4; ++qf)
          o[df][qf] = MFMA16(vf, pq[qf], o[df][qf]);
      }
    }
    __builtin_amdgcn_s_setprio(0);

    asm volatile("s_waitcnt vmcnt(0)" ::: "memory");
    __builtin_amdgcn_s_barrier();
  }

  // epilogue: lsum lane-local (osum rows all equal) -> no cross-lane reduce
  const int bb = n >> 4, h = n & 15;
#pragma unroll
  for (int qf = 0; qf < 4; ++qf) {
    const float inv = 1.0f / osum[qf][0];
    const int q = qt * 256 + w * 64 + qf * 16 + lq;
#pragma unroll
    for (int df = 0; df < 4; ++df) {
      ushort4 pk;
      pk.x = f2bf(o[df][qf][0] * inv);
      pk.y = f2bf(o[df][qf][1] * inv);
      pk.z = f2bf(o[df][qf][2] * inv);
      pk.w = f2bf(o[df][qf][3] * inv);
      *(ushort4*)&Cx[(size_t)(q * 4 + bb) * 1024 + h * 64 + df * 16 + lg * 4] = pk;
    }
  }
}

// ---------------- host launch ----------------
extern "C" void kernel_launch(void* const* d_in, const int* in_sizes, int n_in,
                              void* d_out, int out_size, void* d_ws, size_t ws_size,
                              hipStream_t stream) {
  const float* X = (const float*)d_in[0];    // (2048,4,1024)
  const float* W1 = (const float*)d_in[1];   // (3072,1024)
  const float* Wo = (const float*)d_in[2];   // (1024,1024)
  float* out = (float*)d_out;                // (2048,4,1024) fp32

  char* ws = (char*)d_ws;
  unsigned short* Xb  = (unsigned short*)(ws);              // 16 MB
  unsigned short* W1b = (unsigned short*)(ws + 16777216);   //  6 MB
  unsigned short* Wob = (unsigned short*)(ws + 23068672);   //  2 MB
  unsigned short* Qb  = (unsigned short*)(ws + 25165824);   // 16 MB
  unsigned short* Kb  = (unsigned short*)(ws + 41943040);   // 16 MB
  unsigned short* VTb = (unsigned short*)(ws + 58720256);   // 16 MB
  unsigned short* Cx  = (unsigned short*)(ws + 75497472);   // 16 MB

  k_cvt3<<<12288, 256, 0, stream>>>(X, W1, Wo, Xb, W1b, Wob);
  k_gemm_qkv<<<dim3(64, 12), 512, 0, stream>>>(Xb, W1b, Qb, Kb, VTb);
  k_attn<<<dim3(64, 8), 256, 0, stream>>>(Qb, Kb, VTb, Cx);
  k_gemm_out<<<dim3(64, 4), 512, 0, stream>>>(Cx, Wob, out);
}

// Round 18
// 175.767 us; speedup vs baseline: 1.1526x; 1.0062x over previous
//
#include <hip/hip_runtime.h>
#include <stdint.h>
#include <stddef.h>

// T=2048, B=4, E=1024, H=16, HD=64, N-heads = B*H = 64.
// qkv reshape: f in [0,3072) -> head hq = f/192, s3 = (f/64)%3, d = f%64, n = b*16+hq.
// Layouts: Qb,Kb = [n][t][d] bf16 ; VTb = [n][d][t] bf16 (transposed in GEMM epilogue via LDS).

typedef __attribute__((ext_vector_type(8))) short bf16x8;
typedef __attribute__((ext_vector_type(4))) float f32x4;
typedef __attribute__((ext_vector_type(4))) unsigned int u32x4;

#define MFMA16(a, b, c) __builtin_amdgcn_mfma_f32_16x16x32_bf16((a), (b), (c), 0, 0, 0)

__device__ __forceinline__ unsigned short f2bf(float f) {
  unsigned u = __builtin_bit_cast(unsigned, f);
  u += 0x7fffu + ((u >> 16) & 1u);   // RNE
  return (unsigned short)(u >> 16);
}

__device__ __forceinline__ float fast_exp2(float x) {
#if __has_builtin(__builtin_amdgcn_exp2f)
  return __builtin_amdgcn_exp2f(x);
#else
  return exp2f(x);
#endif
}

__device__ __forceinline__ unsigned cvtpk(float lo, float hi) {
  unsigned r;
  asm volatile("v_cvt_pk_bf16_f32 %0, %1, %2" : "=v"(r) : "v"(lo), "v"(hi));
  return r;
}

// a' = {a.lo32, b.lo32}, b' = {a.hi32, b.hi32}
__device__ __forceinline__ void lane_swap32(unsigned &a, unsigned &b) {
#if __has_builtin(__builtin_amdgcn_permlane32_swap)
  auto r = __builtin_amdgcn_permlane32_swap(a, b, false, false);
  a = r[0]; b = r[1];
#else
  const bool hi = (threadIdx.x & 32) != 0;
  unsigned sa = (unsigned)__shfl_xor((int)a, 32, 64);
  unsigned sb = (unsigned)__shfl_xor((int)b, 32, 64);
  unsigned na = hi ? sb : a;
  unsigned nb = hi ? b : sa;
  a = na; b = nb;
#endif
}

// a' = {a.g0, b.g0, a.g2, b.g2}, b' = {a.g1, b.g1, a.g3, b.g3} (16-lane groups)
__device__ __forceinline__ void lane_swap16(unsigned &a, unsigned &b) {
#if __has_builtin(__builtin_amdgcn_permlane16_swap)
  auto r = __builtin_amdgcn_permlane16_swap(a, b, false, false);
  a = r[0]; b = r[1];
#else
  const bool odd = (threadIdx.x & 16) != 0;
  unsigned sa = (unsigned)__shfl_xor((int)a, 16, 64);
  unsigned sb = (unsigned)__shfl_xor((int)b, 16, 64);
  unsigned na = odd ? sb : a;
  unsigned nb = odd ? b : sa;
  a = na; b = nb;
#endif
}

__device__ __forceinline__ void gload_lds16(const void* g, void* l) {
  __builtin_amdgcn_global_load_lds((const __attribute__((address_space(1))) void*)g,
                                   (__attribute__((address_space(3))) void*)l,
                                   16, 0, 0);
}

// ---------------- fused fp32 -> bf16 convert for X, W1, Wo ----------------
__global__ __launch_bounds__(256) void k_cvt3(const float* __restrict__ X,
                                              const float* __restrict__ W1,
                                              const float* __restrict__ Wo,
                                              unsigned short* __restrict__ Xb,
                                              unsigned short* __restrict__ W1b,
                                              unsigned short* __restrict__ Wob) {
  int i = blockIdx.x * 256 + threadIdx.x;   // float4 index over all three buffers
  const float* src;
  unsigned short* dst;
  int j;
  if (i < 2097152) { src = X; dst = Xb; j = i; }
  else if (i < 2097152 + 786432) { src = W1; dst = W1b; j = i - 2097152; }
  else { src = Wo; dst = Wob; j = i - (2097152 + 786432); }
  const float4 v = ((const float4*)src)[j];
  ushort4 o;
  o.x = f2bf(v.x); o.y = f2bf(v.y); o.z = f2bf(v.z); o.w = f2bf(v.w);
  ((ushort4*)dst)[j] = o;
}

// =============== shared 128x256-tile 2-phase counted-vmcnt GEMM template ===============
// 512 threads / 8 waves (2M x 4N). BK=64 split in two 32-k units. LDS 96KB.
// Ledger (3 loads/thread/unit: A=1, B=2): prologue stages u0,u1 -> vmcnt(3)+barrier;
// each phase: read unit, stage next-step same unit (+3), MFMA, vmcnt(3) BEFORE barrier.

// ---------------- GEMM1: X[8192][1024] x W1t[3072][1024] -> Q/K direct + V transposed ----------------
__global__ __launch_bounds__(512, 2) void k_gemm_qkv(
    const unsigned short* __restrict__ A,
    const unsigned short* __restrict__ Bt,
    unsigned short* __restrict__ Qb,        // [64][2048][64]
    unsigned short* __restrict__ Kb,        // [64][2048][64]
    unsigned short* __restrict__ VTb) {     // [64][64][2048]
  __shared__ __align__(16) char Sm[98304];  // A units: 4x8KB @0; B units: 4x16KB @32768
  char* lAs = Sm;
  char* lBs = Sm + 32768;

  const int tid = threadIdx.x;            // 0..511
  const int l = tid & 63;
  const int wid = tid >> 6;               // 0..7
  const int lr = l & 15, lg = l >> 4;
  const int wr = wid >> 2, wc = wid & 3;  // 2M x 4N
  const int bm = blockIdx.x, bn = blockIdx.y;

  f32x4 acc[4][4] = {};
  const int colF = (lg * 16) ^ (((lr >> 1) & 3) << 4);

  auto STAGE_A = [&](int buf, int kt2, int uk) {
    const int row = tid >> 2;               // 0..127
    const int colb = (tid & 3) * 16;
    const int sw = ((row >> 1) & 3) << 4;
    gload_lds16((const char*)A + (size_t)(bm * 128 + row) * 2048 + kt2 * 128 + uk * 64 +
                    (colb ^ sw),
                lAs + (buf * 2 + uk) * 8192 + tid * 16);
  };
  auto STAGE_B = [&](int buf, int kt2, int uk) {
#pragma unroll
    for (int i = 0; i < 2; ++i) {
      const int idx = i * 512 + tid;        // 0..1023
      const int row = idx >> 2;             // 0..255
      const int colb = (idx & 3) * 16;
      const int sw = ((row >> 1) & 3) << 4;
      gload_lds16((const char*)Bt + (size_t)(bn * 256 + row) * 2048 + kt2 * 128 + uk * 64 +
                      (colb ^ sw),
                  lBs + (buf * 2 + uk) * 16384 + idx * 16);
    }
  };

  // prologue: u0, u1 of step 0 into buf 0; wait u0 (oldest 3), barrier
  STAGE_A(0, 0, 0); STAGE_B(0, 0, 0);
  STAGE_A(0, 0, 1); STAGE_B(0, 0, 1);
  asm volatile("s_waitcnt vmcnt(3)" ::: "memory");
  __builtin_amdgcn_s_barrier();

#pragma unroll 2
  for (int kt = 0; kt < 16; ++kt) {
    const int buf = kt & 1, nbuf = buf ^ 1;
    const int ktn = (kt + 1 < 16) ? kt + 1 : 15;   // tail: dummy restage keeps ledger uniform

#pragma unroll
    for (int uk = 0; uk < 2; ++uk) {
      bf16x8 a[4], b[4];
#pragma unroll
      for (int mf = 0; mf < 4; ++mf)
        a[mf] = *(const bf16x8*)(lAs + (buf * 2 + uk) * 8192 + (wr * 64 + mf * 16 + lr) * 64 + colF);
#pragma unroll
      for (int nf = 0; nf < 4; ++nf)
        b[nf] = *(const bf16x8*)(lBs + (buf * 2 + uk) * 16384 + (wc * 64 + nf * 16 + lr) * 64 + colF);
      STAGE_A(nbuf, ktn, uk);
      STAGE_B(nbuf, ktn, uk);
      __builtin_amdgcn_s_setprio(1);
#pragma unroll
      for (int mf = 0; mf < 4; ++mf)
#pragma unroll
        for (int nf = 0; nf < 4; ++nf)
          acc[mf][nf] = MFMA16(a[mf], b[nf], acc[mf][nf]);
      __builtin_amdgcn_s_setprio(0);
      asm volatile("s_waitcnt vmcnt(3)" ::: "memory");
      __builtin_amdgcn_s_barrier();
    }
  }

  // drain dummy restages before reusing LDS as transpose buffer
  asm volatile("s_waitcnt vmcnt(0)" ::: "memory");
  __syncthreads();

  // Epilogue. Wave col-group f0 is wholly Q, K, or V; d = nf*16+lr in all cases.
  const int f0 = bn * 256 + wc * 64;
  const int s3g = (f0 >> 6) % 3;
  const int hqg = f0 / 192;

  if (s3g != 2) {
    unsigned short* dst = (s3g == 0) ? Qb : Kb;
    const float qscale = (s3g == 0) ? 0.18033688011112042f : 1.0f;  // SCALE*log2(e) into Q
#pragma unroll
    for (int nf = 0; nf < 4; ++nf) {
      const int d = nf * 16 + lr;
#pragma unroll
      for (int mf = 0; mf < 4; ++mf) {
#pragma unroll
        for (int i = 0; i < 4; ++i) {
          const int r = bm * 128 + wr * 64 + mf * 16 + lg * 4 + i;
          const int t = r >> 2, bb2 = r & 3;
          dst[((size_t)(bb2 * 16 + hqg) * 2048 + t) * 64 + d] = f2bf(acc[mf][nf][i] * qscale);
        }
      }
    }
  } else {
    // V: per-wc transpose buffer, 128 rows x pitch 68 shorts = 17408B, stride 24576B
    unsigned short* Tb = (unsigned short*)(Sm + wc * 24576);
#pragma unroll
    for (int nf = 0; nf < 4; ++nf) {
      const int d = nf * 16 + lr;
#pragma unroll
      for (int mf = 0; mf < 4; ++mf) {
#pragma unroll
        for (int i = 0; i < 4; ++i) {
          const int rl = wr * 64 + mf * 16 + lg * 4 + i;   // 0..127
          Tb[rl * 68 + d] = f2bf(acc[mf][nf][i]);
        }
      }
    }
  }
  __syncthreads();
  if (s3g == 2) {
    // both waves of this wc (128 threads) read back & store VT[n][d][t] in 8B chunks
    unsigned short* Tb = (unsigned short*)(Sm + wc * 24576);
    const int u = wr * 64 + l;        // 0..127
    const int d = u >> 1, th = u & 1; // d 0..63, t-half
#pragma unroll
    for (int bb = 0; bb < 4; ++bb) {
      const size_t base = ((size_t)(bb * 16 + hqg) * 64 + d) * 2048 + bm * 32 + th * 16;
#pragma unroll
      for (int tq = 0; tq < 4; ++tq) {
        ushort4 pk;
        pk.x = Tb[((th * 16 + tq * 4 + 0) * 4 + bb) * 68 + d];
        pk.y = Tb[((th * 16 + tq * 4 + 1) * 4 + bb) * 68 + d];
        pk.z = Tb[((th * 16 + tq * 4 + 2) * 4 + bb) * 68 + d];
        pk.w = Tb[((th * 16 + tq * 4 + 3) * 4 + bb) * 68 + d];
        *(ushort4*)&VTb[base + tq * 4] = pk;
      }
    }
  }
}

// ---------------- GEMM4: ctx[8192][1024] x Wot[1024][1024] -> out fp32 (same template) ----------------
__global__ __launch_bounds__(512, 2) void k_gemm_out(
    const unsigned short* __restrict__ A,
    const unsigned short* __restrict__ Bt,
    float* __restrict__ C) {
  __shared__ __align__(16) char Sm[98304];
  char* lAs = Sm;
  char* lBs = Sm + 32768;

  const int tid = threadIdx.x;
  const int l = tid & 63;
  const int wid = tid >> 6;
  const int lr = l & 15, lg = l >> 4;
  const int wr = wid >> 2, wc = wid & 3;
  const int bm = blockIdx.x, bn = blockIdx.y;

  f32x4 acc[4][4] = {};
  const int colF = (lg * 16) ^ (((lr >> 1) & 3) << 4);

  auto STAGE_A = [&](int buf, int kt2, int uk) {
    const int row = tid >> 2;
    const int colb = (tid & 3) * 16;
    const int sw = ((row >> 1) & 3) << 4;
    gload_lds16((const char*)A + (size_t)(bm * 128 + row) * 2048 + kt2 * 128 + uk * 64 +
                    (colb ^ sw),
                lAs + (buf * 2 + uk) * 8192 + tid * 16);
  };
  auto STAGE_B = [&](int buf, int kt2, int uk) {
#pragma unroll
    for (int i = 0; i < 2; ++i) {
      const int idx = i * 512 + tid;
      const int row = idx >> 2;
      const int colb = (idx & 3) * 16;
      const int sw = ((row >> 1) & 3) << 4;
      gload_lds16((const char*)Bt + (size_t)(bn * 256 + row) * 2048 + kt2 * 128 + uk * 64 +
                      (colb ^ sw),
                  lBs + (buf * 2 + uk) * 16384 + idx * 16);
    }
  };

  STAGE_A(0, 0, 0); STAGE_B(0, 0, 0);
  STAGE_A(0, 0, 1); STAGE_B(0, 0, 1);
  asm volatile("s_waitcnt vmcnt(3)" ::: "memory");
  __builtin_amdgcn_s_barrier();

#pragma unroll 2
  for (int kt = 0; kt < 16; ++kt) {
    const int buf = kt & 1, nbuf = buf ^ 1;
    const int ktn = (kt + 1 < 16) ? kt + 1 : 15;

#pragma unroll
    for (int uk = 0; uk < 2; ++uk) {
      bf16x8 a[4], b[4];
#pragma unroll
      for (int mf = 0; mf < 4; ++mf)
        a[mf] = *(const bf16x8*)(lAs + (buf * 2 + uk) * 8192 + (wr * 64 + mf * 16 + lr) * 64 + colF);
#pragma unroll
      for (int nf = 0; nf < 4; ++nf)
        b[nf] = *(const bf16x8*)(lBs + (buf * 2 + uk) * 16384 + (wc * 64 + nf * 16 + lr) * 64 + colF);
      STAGE_A(nbuf, ktn, uk);
      STAGE_B(nbuf, ktn, uk);
      __builtin_amdgcn_s_setprio(1);
#pragma unroll
      for (int mf = 0; mf < 4; ++mf)
#pragma unroll
        for (int nf = 0; nf < 4; ++nf)
          acc[mf][nf] = MFMA16(a[mf], b[nf], acc[mf][nf]);
      __builtin_amdgcn_s_setprio(0);
      asm volatile("s_waitcnt vmcnt(3)" ::: "memory");
      __builtin_amdgcn_s_barrier();
    }
  }

  asm volatile("s_waitcnt vmcnt(0)" ::: "memory");   // drain tail dummy restage

#pragma unroll
  for (int mf = 0; mf < 4; ++mf)
#pragma unroll
    for (int i = 0; i < 4; ++i) {
      const int r = bm * 128 + wr * 64 + mf * 16 + lg * 4 + i;
#pragma unroll
      for (int nf = 0; nf < 4; ++nf)
        C[(size_t)r * 1024 + bn * 256 + wc * 64 + nf * 16 + lr] = acc[mf][nf][i];
    }
}

// ---------------- flash attention: q=256/block, KVBLK=128 dbuf; V in 128B-row sub-buffers ----------------
__global__ __launch_bounds__(256, 2) void k_attn(
    const unsigned short* __restrict__ Qb, const unsigned short* __restrict__ Kb,
    const unsigned short* __restrict__ VTb, unsigned short* __restrict__ Cx) {
  __shared__ __align__(16) unsigned short Ks[2][128 * 64];    // [s][d] 128B rows, swz (row&7)<<4
  __shared__ __align__(16) unsigned short Vt[2][2][64 * 64];  // [half][d][64] 128B rows, swz (d&7)<<4

  const int tid = threadIdx.x;
  const int l = tid & 63, w = tid >> 6;
  const int lq = l & 15, lg = l >> 4;
  const int n = blockIdx.x, qt = blockIdx.y;   // x = head -> same-head blocks on one XCD

  const unsigned short* Qh = Qb + (size_t)n * (2048 * 64);
  const unsigned short* Kh = Kb + (size_t)n * (2048 * 64);
  const unsigned short* Vh = VTb + (size_t)n * (64 * 2048);

  // Q fragments (B-operand of swapped QK^T): q = qt*256 + w*64 + qf*16 + lq
  bf16x8 aq[4][2];
#pragma unroll
  for (int qf = 0; qf < 4; ++qf)
#pragma unroll
    for (int kd = 0; kd < 2; ++kd)
      aq[qf][kd] = *(const bf16x8*)&Qh[(size_t)(qt * 256 + w * 64 + qf * 16 + lq) * 64 +
                                       kd * 32 + lg * 8];

  f32x4 o[4][4] = {};       // O^T acc: [df][qf]; lane: q = lq, d = df*16 + lg*4 + i
  f32x4 osum[4] = {};       // denominator acc via ones-row MFMA

  const short ONE = (short)0x3F80;
  const bf16x8 aones = {ONE, ONE, ONE, ONE, ONE, ONE, ONE, ONE};

  char* Ksl = (char*)&Ks[0][0];
  char* Vtl = (char*)&Vt[0][0][0];

  // stage one 128-key tile: K[128][64] (16KB) + V as two [d][64] halves (16KB)
  auto STAGE = [&](int buf, int st) {
    const int s0 = st * 128;
#pragma unroll
    for (int it = 0; it < 4; ++it) {
      const int off = (it * 256 + tid) * 16;
      const int row = off >> 7;                               // 0..127 (key)
      const int colb = (off & 127) ^ ((row & 7) << 4);
      gload_lds16((const char*)Kh + ((size_t)(s0 + row) << 7) + colb, Ksl + buf * 16384 + off);
    }
    // V halves: each 8KB = [64 d][128B], global cols s0 + half*64 .. +64
#pragma unroll
    for (int it = 0; it < 4; ++it) {
      const int off = (it * 256 + tid) * 16;                  // 0..16383
      const int half = off >> 13;                             // 0..1
      const int ino = off & 8191;
      const int row = ino >> 7;                               // d 0..63
      const int colb = (ino & 127) ^ ((row & 7) << 4);
      gload_lds16((const char*)Vh + ((size_t)row << 12) + ((s0 + half * 64) << 1) + colb,
                  Vtl + buf * 16384 + off);
    }
  };

  STAGE(0, 0);
  asm volatile("s_waitcnt vmcnt(0)" ::: "memory");
  __builtin_amdgcn_s_barrier();

#pragma unroll 2
  for (int st = 0; st < 16; ++st) {
    const int cur = st & 1;
    if (st + 1 < 16) STAGE(cur ^ 1, st + 1);   // prefetch next 128-key tile

    const char* Kc = Ksl + cur * 16384;
    const char* Vc = Vtl + cur * 16384;

    __builtin_amdgcn_s_setprio(1);
#pragma unroll
    for (int kb = 0; kb < 4; ++kb) {
      // K fragments for s-block [kb*32, kb*32+32): rows kb*32 + sfl*16 + lq
      bf16x8 kf[2][2];
#pragma unroll
      for (int sfl = 0; sfl < 2; ++sfl) {
        const int rowk = kb * 32 + sfl * 16 + lq;
        const int sw = (rowk & 7) << 4;
        kf[sfl][0] = *(const bf16x8*)(Kc + ((rowk * 128 + lg * 16) ^ sw));
        kf[sfl][1] = *(const bf16x8*)(Kc + ((rowk * 128 + 64 + lg * 16) ^ sw));
      }

      // QK^T + exp2 + in-register P->B-frag exchange, per qf
      bf16x8 pq[4];
#pragma unroll
      for (int qf = 0; qf < 4; ++qf) {
        f32x4 s0 = {0.f, 0.f, 0.f, 0.f};
        f32x4 s1 = {0.f, 0.f, 0.f, 0.f};
        s0 = MFMA16(kf[0][0], aq[qf][0], s0);
        s0 = MFMA16(kf[0][1], aq[qf][1], s0);
        s1 = MFMA16(kf[1][0], aq[qf][0], s1);
        s1 = MFMA16(kf[1][1], aq[qf][1], s1);
#pragma unroll
        for (int i = 0; i < 4; ++i) {
          s0[i] = fast_exp2(s0[i]);
          s1[i] = fast_exp2(s1[i]);
        }
        unsigned w0 = cvtpk(s0[0], s0[1]);
        unsigned w1 = cvtpk(s0[2], s0[3]);
        unsigned w2 = cvtpk(s1[0], s1[1]);
        unsigned w3 = cvtpk(s1[2], s1[3]);
        lane_swap32(w0, w2);
        lane_swap32(w1, w3);
        lane_swap16(w0, w2);
        lane_swap16(w1, w3);
        u32x4 t4 = {w0, w1, w2, w3};
        pq[qf] = __builtin_bit_cast(bf16x8, t4);
        osum[qf] = MFMA16(aones, pq[qf], osum[qf]);   // denominator via matrix pipe
      }

      // PV: V sub-buffer kb>>1 (128B rows, conflict-free), inner half kb&1
      const char* Vs = Vc + (kb >> 1) * 8192;
      const int kk = kb & 1;
#pragma unroll
      for (int df = 0; df < 4; ++df) {
        const int rowd = df * 16 + lq;
        const int sw = (rowd & 7) << 4;
        bf16x8 vf = *(const bf16x8*)(Vs + ((rowd * 128 + kk * 64 + lg * 16) ^ sw));
#pragma unroll
        for (int qf = 0; qf < 4; ++qf)
          o[df][qf] = MFMA16(vf, pq[qf], o[df][qf]);
      }
    }
    __builtin_amdgcn_s_setprio(0);

    asm volatile("s_waitcnt vmcnt(0)" ::: "memory");
    __builtin_amdgcn_s_barrier();
  }

  // epilogue: lsum lane-local (osum rows all equal) -> no cross-lane reduce
  const int bb = n >> 4, h = n & 15;
#pragma unroll
  for (int qf = 0; qf < 4; ++qf) {
    const float inv = 1.0f / osum[qf][0];
    const int q = qt * 256 + w * 64 + qf * 16 + lq;
#pragma unroll
    for (int df = 0; df < 4; ++df) {
      ushort4 pk;
      pk.x = f2bf(o[df][qf][0] * inv);
      pk.y = f2bf(o[df][qf][1] * inv);
      pk.z = f2bf(o[df][qf][2] * inv);
      pk.w = f2bf(o[df][qf][3] * inv);
      *(ushort4*)&Cx[(size_t)(q * 4 + bb) * 1024 + h * 64 + df * 16 + lg * 4] = pk;
    }
  }
}

// ---------------- host launch ----------------
extern "C" void kernel_launch(void* const* d_in, const int* in_sizes, int n_in,
                              void* d_out, int out_size, void* d_ws, size_t ws_size,
                              hipStream_t stream) {
  const float* X = (const float*)d_in[0];    // (2048,4,1024)
  const float* W1 = (const float*)d_in[1];   // (3072,1024)
  const float* Wo = (const float*)d_in[2];   // (1024,1024)
  float* out = (float*)d_out;                // (2048,4,1024) fp32

  char* ws = (char*)d_ws;
  unsigned short* Xb  = (unsigned short*)(ws);              // 16 MB
  unsigned short* W1b = (unsigned short*)(ws + 16777216);   //  6 MB
  unsigned short* Wob = (unsigned short*)(ws + 23068672);   //  2 MB
  unsigned short* Qb  = (unsigned short*)(ws + 25165824);   // 16 MB
  unsigned short* Kb  = (unsigned short*)(ws + 41943040);   // 16 MB
  unsigned short* VTb = (unsigned short*)(ws + 58720256);   // 16 MB
  unsigned short* Cx  = (unsigned short*)(ws + 75497472);   // 16 MB

  k_cvt3<<<12288, 256, 0, stream>>>(X, W1, Wo, Xb, W1b, Wob);
  k_gemm_qkv<<<dim3(64, 12), 512, 0, stream>>>(Xb, W1b, Qb, Kb, VTb);
  k_attn<<<dim3(64, 8), 256, 0, stream>>>(Qb, Kb, VTb, Cx);
  k_gemm_out<<<dim3(64, 4), 512, 0, stream>>>(Cx, Wob, out);
}